// Round 17
// baseline (522.016 us; speedup 1.0000x reference)
//
#include <hip/hip_runtime.h>
#include <hip/hip_bf16.h>

#define N_NODES 50000
#define N_EDGES 800000
#define N_GRAPHS 256
#define HID 64
#define KOUT 192   // K * OUT
#define EPS 1e-5f
#define NB1 196    // ceil(N_NODES / 256)

// ---------------- degree ----------------
__global__ void k_deg(const int* __restrict__ dst, int* __restrict__ deg) {
    int i = blockIdx.x * blockDim.x + threadIdx.x;
    if (i < N_EDGES) atomicAdd(&deg[dst[i]], 1);
}

// ---------------- hierarchical exclusive scan of deg -> rowptr ----------------
__global__ __launch_bounds__(256) void k_scan1(const int* __restrict__ deg,
                                               int* __restrict__ rowptr,
                                               int* __restrict__ blocksum) {
    __shared__ int sc[256];
    int t = threadIdx.x;
    int i = blockIdx.x * 256 + t;
    int v = (i < N_NODES) ? deg[i] : 0;
    sc[t] = v;
    __syncthreads();
    for (int off = 1; off < 256; off <<= 1) {
        int u = (t >= off) ? sc[t - off] : 0;
        __syncthreads();
        sc[t] += u;
        __syncthreads();
    }
    if (i < N_NODES) rowptr[i] = sc[t] - v;  // exclusive local prefix
    if (t == 255) blocksum[blockIdx.x] = sc[255];
}

__global__ __launch_bounds__(256) void k_scan2(const int* __restrict__ blocksum,
                                               int* __restrict__ blockoff) {
    __shared__ int sc[256];
    int t = threadIdx.x;
    int v = (t < NB1) ? blocksum[t] : 0;
    sc[t] = v;
    __syncthreads();
    for (int off = 1; off < 256; off <<= 1) {
        int u = (t >= off) ? sc[t - off] : 0;
        __syncthreads();
        sc[t] += u;
        __syncthreads();
    }
    if (t < NB1) blockoff[t] = sc[t] - v;
}

// rowptr[i] += blockoff[i>>8]; cursor[i] = rowptr[i]; rowptr[N]=E
__global__ __launch_bounds__(256) void k_scan3(int* __restrict__ rowptr,
                                               const int* __restrict__ blockoff,
                                               int* __restrict__ cursor) {
    int i = blockIdx.x * 256 + threadIdx.x;
    if (i < N_NODES) {
        int r = rowptr[i] + blockoff[i >> 8];
        rowptr[i] = r;
        cursor[i] = r;
    }
    if (i == 0) rowptr[N_NODES] = N_EDGES;
}

// ---------------- scatter edges into CSR (by dst): src only, 4B/edge ----------------
__global__ void k_scatter(const int* __restrict__ src, const int* __restrict__ dst,
                          int* __restrict__ cursor, int* __restrict__ csr_src) {
    int e = blockIdx.x * blockDim.x + threadIdx.x;
    if (e >= N_EDGES) return;
    int s = src[e], d = dst[e];
    int p = atomicAdd(&cursor[d], 1);
    csr_src[p] = s;
}

// ---------------- gaussian from degrees (shared by table + fallback) ----------------
__device__ __forceinline__ float4 gauss_direct(int degs, int degd,
                                               const float* __restrict__ mu,
                                               const float* __restrict__ isg,
                                               const float* __restrict__ ppw,
                                               const float* __restrict__ ppb) {
    float p0 = rsqrtf((float)degs + 1.0f);
    float p1 = rsqrtf((float)degd + 1.0f);
    float u0 = tanhf(fmaf(p1, ppw[1], fmaf(p0, ppw[0], ppb[0])));
    float u1 = tanhf(fmaf(p1, ppw[3], fmaf(p0, ppw[2], ppb[1])));
    float4 g;
    float t0, t1;
    t0 = (u0 - mu[0]) * isg[0]; t1 = (u1 - mu[1]) * isg[1];
    g.x = __expf(-0.5f * (t0 * t0 + t1 * t1));
    t0 = (u0 - mu[2]) * isg[2]; t1 = (u1 - mu[3]) * isg[3];
    g.y = __expf(-0.5f * (t0 * t0 + t1 * t1));
    t0 = (u0 - mu[4]) * isg[4]; t1 = (u1 - mu[5]) * isg[5];
    g.z = __expf(-0.5f * (t0 * t0 + t1 * t1));
    g.w = 0.f;
    return g;
}

// all 4 layers' 64x64 gauss tables
__global__ __launch_bounds__(256) void k_tables(const float* __restrict__ mu,
                                                const float* __restrict__ isg,
                                                const float* __restrict__ ppw,
                                                const float* __restrict__ ppb,
                                                float4* __restrict__ tbl) {
    int i = blockIdx.x * 256 + threadIdx.x;  // 4*4096
    int l = i >> 12;
    int idx = i & 4095;
    tbl[i] = gauss_direct(idx >> 6, idx & 63, mu + l * 6, isg + l * 6,
                          ppw + l * 4, ppb + l * 2);
}

// ---------------- weight transpose: wt4[l][q*12+m][cp] = {w(q*48+4m+i, cp)} ----------------
// w(j, cp) = fc_w[l][(j>>6)*64 + cp][j&63]; per-layer 48*64 = 3072 float4 entries
__global__ __launch_bounds__(256) void k_wprep(const float* __restrict__ fcw,
                                               float4* __restrict__ wt4) {
    int i = blockIdx.x * 256 + threadIdx.x;   // 4 * 3072 = 12288
    if (i >= 4 * 48 * 64) return;
    int l = i / 3072;         // layer
    int r = i - l * 3072;     // qm*64 + cp
    int qm = r >> 6;          // q*12+m  (0..47)
    int cp = r & 63;
    int j0 = qm * 4;          // k-index base
    const float* base = fcw + (size_t)l * KOUT * HID;
    float4 v;
    v.x = base[((j0 + 0) >> 6) * 4096 + cp * 64 + ((j0 + 0) & 63)];
    v.y = base[((j0 + 1) >> 6) * 4096 + cp * 64 + ((j0 + 1) & 63)];
    v.z = base[((j0 + 2) >> 6) * 4096 + cp * 64 + ((j0 + 2) & 63)];
    v.w = base[((j0 + 3) >> 6) * 4096 + cp * 64 + ((j0 + 3) & 63)];
    wt4[i] = v;
}

// ---------------- pull aggregation: one wave per node (r13 structure, csr = src only) ----------------
// Gauss weight recomputed from degrees: ds = deg[src] (wave-uniform s_load, L2-hot 200KB),
// idx = ds*64+dd in SALU -> tbl (scalar). Fallback path for deg>=64 identical to k_tables math.
template <bool L0>
__global__ __launch_bounds__(256) void k_pull(const int* __restrict__ rowptr,
                                              const int* __restrict__ csr_src,
                                              const float4* __restrict__ tbl,
                                              const float* __restrict__ h,
                                              const int* __restrict__ h_idx,
                                              const float* __restrict__ emb,
                                              const int* __restrict__ deg,
                                              const float* __restrict__ mu,
                                              const float* __restrict__ isg,
                                              const float* __restrict__ ppw,
                                              const float* __restrict__ ppb,
                                              float* __restrict__ a3) {
    int n = blockIdx.x * 4 + (threadIdx.x >> 6);
    n = __builtin_amdgcn_readfirstlane(n);
    if (n >= N_NODES) return;
    int lane = threadIdx.x & 63;
    int beg = rowptr[n];
    int end = rowptr[n + 1];
    int dd = end - beg;
    float a0 = 0.f, a1 = 0.f, a2 = 0.f;

    auto getg = [&](int s) -> float4 {
        int ds = deg[s];  // wave-uniform scalar load
        if (__builtin_expect(ds < 64 && dd < 64, 1)) return tbl[ds * 64 + dd];
        return gauss_direct(ds, dd, mu, isg, ppw, ppb);
    };
    auto geth = [&](int s) -> float {
        if (L0) return emb[h_idx[s] * HID + lane];
        return h[(size_t)s * HID + lane];
    };

    int p = beg;
    for (; p + 8 <= end; p += 8) {
        int s[8];
#pragma unroll
        for (int u = 0; u < 8; ++u) s[u] = csr_src[p + u];
        float hv[8];
#pragma unroll
        for (int u = 0; u < 8; ++u) hv[u] = geth(s[u]);
#pragma unroll
        for (int u = 0; u < 8; ++u) {
            float4 g = getg(s[u]);
            a0 = fmaf(g.x, hv[u], a0); a1 = fmaf(g.y, hv[u], a1); a2 = fmaf(g.z, hv[u], a2);
        }
    }
    for (; p + 4 <= end; p += 4) {
        int s0 = csr_src[p], s1 = csr_src[p + 1], s2 = csr_src[p + 2], s3 = csr_src[p + 3];
        float h0 = geth(s0), h1 = geth(s1), h2 = geth(s2), h3 = geth(s3);
        float4 g0 = getg(s0), g1 = getg(s1), g2 = getg(s2), g3 = getg(s3);
        a0 = fmaf(g0.x, h0, a0); a1 = fmaf(g0.y, h0, a1); a2 = fmaf(g0.z, h0, a2);
        a0 = fmaf(g1.x, h1, a0); a1 = fmaf(g1.y, h1, a1); a2 = fmaf(g1.z, h1, a2);
        a0 = fmaf(g2.x, h2, a0); a1 = fmaf(g2.y, h2, a1); a2 = fmaf(g2.z, h2, a2);
        a0 = fmaf(g3.x, h3, a0); a1 = fmaf(g3.y, h3, a1); a2 = fmaf(g3.z, h3, a2);
    }
    for (; p < end; ++p) {
        int s0 = csr_src[p];
        float h0 = geth(s0);
        float4 g0 = getg(s0);
        a0 = fmaf(g0.x, h0, a0); a1 = fmaf(g0.y, h0, a1); a2 = fmaf(g0.z, h0, a2);
    }
    float* out = a3 + (size_t)n * KOUT + lane;
    out[0] = a0;
    out[64] = a1;
    out[128] = a2;
}

// ---------------- fc2: weights (pre-transposed) coalesced, small batch, grid-stride ----------------
// 256 threads = 4 waves; wave q owns k-range [q*48, q*48+48); 8 nodes/batch.
// Weight prologue: 12 coalesced float4 loads from wt4 (12 KB/layer, L2-hot).
#define FC2_B 8
#define FC2_GRID 2048
__global__ __launch_bounds__(256) void k_fc2(const float* __restrict__ a3,
                                             const float4* __restrict__ wt4,
                                             float* __restrict__ agg,
                                             float* __restrict__ bnpart) {
    __shared__ float4 sa4[FC2_B][49];   // 6.3 KB
    __shared__ float sp[4][FC2_B][65];  // 8.3 KB
    __shared__ float bnp[4][128];       // 2 KB
    int t = threadIdx.x;
    int cp = t & 63;
    int q = t >> 6;
    float4 wv[12];
#pragma unroll
    for (int m = 0; m < 12; ++m) wv[m] = wt4[(q * 12 + m) * 64 + cp];
    float bnS = 0.f, bnQ = 0.f;
    const float4* a3v = (const float4*)a3;
    for (int base = blockIdx.x * FC2_B; base < N_NODES; base += FC2_GRID * FC2_B) {
        __syncthreads();  // protect sa4/sp from previous batch
        // stage 8 nodes x 48 float4 = 384 -> coalesced
        for (int ii = t; ii < FC2_B * 48; ii += 256) {
            int nn = ii / 48, jj = ii - nn * 48;
            int node = base + nn;
            sa4[nn][jj] = (node < N_NODES) ? a3v[(size_t)node * 48 + jj]
                                           : make_float4(0.f, 0.f, 0.f, 0.f);
        }
        __syncthreads();
        float acc[FC2_B];
#pragma unroll
        for (int nn = 0; nn < FC2_B; ++nn) acc[nn] = 0.f;
#pragma unroll
        for (int m = 0; m < 12; ++m) {
            float4 wm = wv[m];
#pragma unroll
            for (int nn = 0; nn < FC2_B; ++nn) {
                float4 s4 = sa4[nn][q * 12 + m];  // wave-wide broadcast, conflict-free
                acc[nn] = fmaf(s4.x, wm.x, acc[nn]);
                acc[nn] = fmaf(s4.y, wm.y, acc[nn]);
                acc[nn] = fmaf(s4.z, wm.z, acc[nn]);
                acc[nn] = fmaf(s4.w, wm.w, acc[nn]);
            }
        }
#pragma unroll
        for (int nn = 0; nn < FC2_B; ++nn) sp[q][nn][cp] = acc[nn];
        __syncthreads();
        // reduce: thread covers nodes nn = q, q+4 at channel cp
#pragma unroll
        for (int i = 0; i < 2; ++i) {
            int nn = q + i * 4;
            int node = base + nn;
            if (node < N_NODES) {
                float v = sp[0][nn][cp] + sp[1][nn][cp] + sp[2][nn][cp] + sp[3][nn][cp];
                agg[(size_t)node * HID + cp] = v;
                bnS += v;
                bnQ += v * v;
            }
        }
    }
    // deterministic in-block BN reduce: fixed order, no atomics; channel-major store
    __syncthreads();
    bnp[q][cp] = bnS;
    bnp[q][64 + cp] = bnQ;
    __syncthreads();
    if (t < 128) {
        float v = bnp[0][t] + bnp[1][t] + bnp[2][t] + bnp[3][t];
        bnpart[(size_t)t * FC2_GRID + blockIdx.x] = v;
    }
}

// ---------------- deterministic reduce of bnpart -> bnsum (128 blocks, coalesced) ----------------
__global__ __launch_bounds__(256) void k_bnred2(const float* __restrict__ bnpart,
                                                float* __restrict__ bnsum) {
    __shared__ float red[256];
    int c = blockIdx.x;   // channel 0..127
    int t = threadIdx.x;
    float acc = 0.f;
#pragma unroll
    for (int i = 0; i < FC2_GRID / 256; ++i)
        acc += bnpart[(size_t)c * FC2_GRID + i * 256 + t];
    red[t] = acc;
    __syncthreads();
    for (int off = 128; off > 0; off >>= 1) {
        if (t < off) red[t] += red[t + off];
        __syncthreads();
    }
    if (t == 0) bnsum[c] = red[0];
}

// ---------------- BN finalize + apply + residual (float4) ----------------
template <bool L0>
__global__ __launch_bounds__(256) void k_bnapply(const float4* __restrict__ agg4,
                                                 const float* __restrict__ bnsum,
                                                 const float* __restrict__ bng,
                                                 const float* __restrict__ bnb,
                                                 const int* __restrict__ h_idx,
                                                 const float4* __restrict__ emb4,
                                                 float4* __restrict__ h4) {
    __shared__ float ssc[128];
    int t = threadIdx.x;
    if (t < 64) {
        const float invN = 1.0f / (float)N_NODES;
        float mean = bnsum[t] * invN;
        float var = bnsum[64 + t] * invN - mean * mean;
        float scale = bng[t] * rsqrtf(var + EPS);
        ssc[t] = scale;
        ssc[64 + t] = bnb[t] - mean * scale;
    }
    __syncthreads();
    int i = blockIdx.x * 256 + t;  // over N_NODES*16 float4s
    if (i < N_NODES * 16) {
        int c4 = (i & 15) * 4;
        float4 ag = agg4[i];
        float4 hn;
        hn.x = fmaxf(fmaf(ag.x, ssc[c4 + 0], ssc[64 + c4 + 0]), 0.f);
        hn.y = fmaxf(fmaf(ag.y, ssc[c4 + 1], ssc[64 + c4 + 1]), 0.f);
        hn.z = fmaxf(fmaf(ag.z, ssc[c4 + 2], ssc[64 + c4 + 2]), 0.f);
        hn.w = fmaxf(fmaf(ag.w, ssc[c4 + 3], ssc[64 + c4 + 3]), 0.f);
        float4 base;
        if (L0) {
            int n = i >> 4;
            base = emb4[h_idx[n] * 16 + (i & 15)];
        } else {
            base = h4[i];
        }
        base.x += hn.x; base.y += hn.y; base.z += hn.z; base.w += hn.w;
        h4[i] = base;
    }
}

// ---------------- readout: wave per 64-node chunk, run-length accumulate ----------------
__global__ __launch_bounds__(256) void k_readout(const float* __restrict__ h,
                                                 const int* __restrict__ gid,
                                                 float* __restrict__ hg,
                                                 float* __restrict__ cnt) {
    int chunk = blockIdx.x * 4 + (threadIdx.x >> 6);
    int lane = threadIdx.x & 63;
    int n0 = chunk * 64;
    if (n0 >= N_NODES) return;
    int n1 = min(n0 + 64, N_NODES);
    int curg = gid[n0];
    float acc = 0.f;
    int count = 0;
    for (int n = n0; n < n1; ++n) {
        int g = gid[n];
        if (g != curg) {
            atomicAdd(&hg[(size_t)curg * HID + lane], acc);
            if (lane == 0) atomicAdd(&cnt[curg], (float)count);
            curg = g; acc = 0.f; count = 0;
        }
        acc += h[(size_t)n * HID + lane];
        ++count;
    }
    atomicAdd(&hg[(size_t)curg * HID + lane], acc);
    if (lane == 0) atomicAdd(&cnt[curg], (float)count);
}

// ---------------- MLP readout ----------------
__global__ __launch_bounds__(256) void k_mlp(const float* __restrict__ hg,
                                             const float* __restrict__ cnt,
                                             const float* __restrict__ w1, const float* __restrict__ b1,
                                             const float* __restrict__ w2, const float* __restrict__ b2,
                                             const float* __restrict__ w3, const float* __restrict__ b3,
                                             float* __restrict__ out) {
    int g = threadIdx.x;  // 256 threads, single block
    float inv = 1.0f / fmaxf(cnt[g], 1.0f);
    float x[HID];
#pragma unroll
    for (int i = 0; i < HID; ++i) x[i] = hg[(size_t)g * HID + i] * inv;
    float y1[32];
#pragma unroll
    for (int j = 0; j < 32; ++j) {
        float acc = b1[j];
#pragma unroll
        for (int i = 0; i < HID; ++i) acc = fmaf(x[i], w1[j * HID + i], acc);
        y1[j] = fmaxf(acc, 0.f);
    }
    float y2[16];
#pragma unroll
    for (int j = 0; j < 16; ++j) {
        float acc = b2[j];
#pragma unroll
        for (int i = 0; i < 32; ++i) acc = fmaf(y1[i], w2[j * 32 + i], acc);
        y2[j] = fmaxf(acc, 0.f);
    }
    float acc = b3[0];
#pragma unroll
    for (int i = 0; i < 16; ++i) acc = fmaf(y2[i], w3[i], acc);
    out[g] = acc;
}

extern "C" void kernel_launch(void* const* d_in, const int* in_sizes, int n_in,
                              void* d_out, int out_size, void* d_ws, size_t ws_size,
                              hipStream_t stream) {
    const int* h_idx = (const int*)d_in[0];
    const int* src = (const int*)d_in[1];
    const int* dst = (const int*)d_in[2];
    const int* gid = (const int*)d_in[3];
    const float* emb = (const float*)d_in[4];
    const float* fc_w = (const float*)d_in[5];
    const float* mu = (const float*)d_in[6];
    const float* isg = (const float*)d_in[7];
    const float* bng = (const float*)d_in[8];
    const float* bnb = (const float*)d_in[9];
    const float* ppw = (const float*)d_in[10];
    const float* ppb = (const float*)d_in[11];
    const float* w1 = (const float*)d_in[12];
    const float* b1 = (const float*)d_in[13];
    const float* w2 = (const float*)d_in[14];
    const float* b2 = (const float*)d_in[15];
    const float* w3 = (const float*)d_in[16];
    const float* b3 = (const float*)d_in[17];

    char* ws = (char*)d_ws;
    size_t o = 0;
    auto take = [&](size_t bytes) -> char* {
        char* p = ws + o;
        o += (bytes + 255) & ~(size_t)255;
        return p;
    };
    int* deg = (int*)take((size_t)N_NODES * 4);
    int* cursor = (int*)take((size_t)N_NODES * 4);
    int* rowptr = (int*)take((size_t)(N_NODES + 1) * 4);
    int* blocksum = (int*)take((size_t)NB1 * 4);
    int* blockoff = (int*)take((size_t)NB1 * 4);
    int* csr_src = (int*)take((size_t)N_EDGES * 4);
    float4* tbl = (float4*)take((size_t)4 * 4096 * 16);
    float4* wt4 = (float4*)take((size_t)4 * 48 * 64 * 16);  // 192 KB
    float* h = (float*)take((size_t)N_NODES * HID * 4);
    float* a3 = (float*)take((size_t)N_NODES * KOUT * 4);
    float* agg = (float*)take((size_t)N_NODES * HID * 4);
    float* bnpart = (float*)take((size_t)128 * FC2_GRID * 4);  // 1 MB channel-major
    float* bnsum = (float*)take(128 * 4);
    float* hg = (float*)take((size_t)N_GRAPHS * HID * 4);
    float* cnt = (float*)take((size_t)N_GRAPHS * 4);

    hipMemsetAsync(deg, 0, (size_t)N_NODES * 4, stream);
    hipMemsetAsync(hg, 0, (size_t)(N_GRAPHS * HID + N_GRAPHS) * 4, stream);

    k_deg<<<(N_EDGES + 255) / 256, 256, 0, stream>>>(dst, deg);
    k_scan1<<<NB1, 256, 0, stream>>>(deg, rowptr, blocksum);
    k_scan2<<<1, 256, 0, stream>>>(blocksum, blockoff);
    k_scan3<<<NB1, 256, 0, stream>>>(rowptr, blockoff, cursor);
    k_scatter<<<(N_EDGES + 255) / 256, 256, 0, stream>>>(src, dst, cursor, csr_src);
    k_tables<<<(4 * 4096) / 256, 256, 0, stream>>>(mu, isg, ppw, ppb, tbl);
    k_wprep<<<(4 * 48 * 64 + 255) / 256, 256, 0, stream>>>(fc_w, wt4);

    for (int l = 0; l < 4; ++l) {
        const float* mul = mu + l * 6;
        const float* isgl = isg + l * 6;
        const float* ppwl = ppw + l * 4;
        const float* ppbl = ppb + l * 2;
        const float4* tbll = tbl + (size_t)l * 4096;
        if (l == 0)
            k_pull<true><<<(N_NODES + 3) / 4, 256, 0, stream>>>(rowptr, csr_src, tbll, h,
                h_idx, emb, deg, mul, isgl, ppwl, ppbl, a3);
        else
            k_pull<false><<<(N_NODES + 3) / 4, 256, 0, stream>>>(rowptr, csr_src, tbll, h,
                h_idx, emb, deg, mul, isgl, ppwl, ppbl, a3);
        k_fc2<<<FC2_GRID, 256, 0, stream>>>(
            a3, wt4 + (size_t)l * 48 * 64, agg, bnpart);
        k_bnred2<<<128, 256, 0, stream>>>(bnpart, bnsum);
        if (l == 0)
            k_bnapply<true><<<(N_NODES * 16 + 255) / 256, 256, 0, stream>>>(
                (const float4*)agg, bnsum, bng + l * 64, bnb + l * 64,
                h_idx, (const float4*)emb, (float4*)h);
        else
            k_bnapply<false><<<(N_NODES * 16 + 255) / 256, 256, 0, stream>>>(
                (const float4*)agg, bnsum, bng + l * 64, bnb + l * 64,
                h_idx, (const float4*)emb, (float4*)h);
    }

    k_readout<<<(N_NODES / 64 + 3) / 4 + 1, 256, 0, stream>>>(h, gid, hg, cnt);
    k_mlp<<<1, 256, 0, stream>>>(hg, cnt, w1, b1, w2, b2, w3, b3, (float*)d_out);
}

// Round 18
// 441.458 us; speedup vs baseline: 1.1825x; 1.1825x over previous
//
#include <hip/hip_runtime.h>
#include <hip/hip_bf16.h>

#define N_NODES 50000
#define N_EDGES 800000
#define N_GRAPHS 256
#define HID 64
#define KOUT 192   // K * OUT
#define EPS 1e-5f
#define NB1 196    // ceil(N_NODES / 256)

__device__ __forceinline__ unsigned short f2bf(float x) {
    unsigned u = __float_as_uint(x);
    unsigned r = (u + 0x7FFFu + ((u >> 16) & 1u)) >> 16;  // round-nearest-even
    return (unsigned short)r;
}

// ---------------- degree ----------------
__global__ void k_deg(const int* __restrict__ dst, int* __restrict__ deg) {
    int i = blockIdx.x * blockDim.x + threadIdx.x;
    if (i < N_EDGES) atomicAdd(&deg[dst[i]], 1);
}

// ---------------- hierarchical exclusive scan of deg -> rowptr ----------------
__global__ __launch_bounds__(256) void k_scan1(const int* __restrict__ deg,
                                               int* __restrict__ rowptr,
                                               int* __restrict__ blocksum) {
    __shared__ int sc[256];
    int t = threadIdx.x;
    int i = blockIdx.x * 256 + t;
    int v = (i < N_NODES) ? deg[i] : 0;
    sc[t] = v;
    __syncthreads();
    for (int off = 1; off < 256; off <<= 1) {
        int u = (t >= off) ? sc[t - off] : 0;
        __syncthreads();
        sc[t] += u;
        __syncthreads();
    }
    if (i < N_NODES) rowptr[i] = sc[t] - v;  // exclusive local prefix
    if (t == 255) blocksum[blockIdx.x] = sc[255];
}

__global__ __launch_bounds__(256) void k_scan2(const int* __restrict__ blocksum,
                                               int* __restrict__ blockoff) {
    __shared__ int sc[256];
    int t = threadIdx.x;
    int v = (t < NB1) ? blocksum[t] : 0;
    sc[t] = v;
    __syncthreads();
    for (int off = 1; off < 256; off <<= 1) {
        int u = (t >= off) ? sc[t - off] : 0;
        __syncthreads();
        sc[t] += u;
        __syncthreads();
    }
    if (t < NB1) blockoff[t] = sc[t] - v;
}

// rowptr[i] += blockoff[i>>8]; cursor[i] = rowptr[i]; rowptr[N]=E
__global__ __launch_bounds__(256) void k_scan3(int* __restrict__ rowptr,
                                               const int* __restrict__ blockoff,
                                               int* __restrict__ cursor) {
    int i = blockIdx.x * 256 + threadIdx.x;
    if (i < N_NODES) {
        int r = rowptr[i] + blockoff[i >> 8];
        rowptr[i] = r;
        cursor[i] = r;
    }
    if (i == 0) rowptr[N_NODES] = N_EDGES;
}

// ---------------- scatter edges into CSR (by dst), with gauss-table index ----------------
__global__ void k_scatter(const int* __restrict__ src, const int* __restrict__ dst,
                          const int* __restrict__ deg, int* __restrict__ cursor,
                          int2* __restrict__ csr_e) {
    int e = blockIdx.x * blockDim.x + threadIdx.x;
    if (e >= N_EDGES) return;
    int s = src[e], d = dst[e];
    int p = atomicAdd(&cursor[d], 1);
    int ds = deg[s], dd = deg[d];
    int idx = (ds < 64 && dd < 64) ? (ds * 64 + dd) : -1;
    csr_e[p] = make_int2(s, idx);
}

// ---------------- gaussian from degrees (shared by table + fallback) ----------------
__device__ __forceinline__ float4 gauss_direct(int degs, int degd,
                                               const float* __restrict__ mu,
                                               const float* __restrict__ isg,
                                               const float* __restrict__ ppw,
                                               const float* __restrict__ ppb) {
    float p0 = rsqrtf((float)degs + 1.0f);
    float p1 = rsqrtf((float)degd + 1.0f);
    float u0 = tanhf(fmaf(p1, ppw[1], fmaf(p0, ppw[0], ppb[0])));
    float u1 = tanhf(fmaf(p1, ppw[3], fmaf(p0, ppw[2], ppb[1])));
    float4 g;
    float t0, t1;
    t0 = (u0 - mu[0]) * isg[0]; t1 = (u1 - mu[1]) * isg[1];
    g.x = __expf(-0.5f * (t0 * t0 + t1 * t1));
    t0 = (u0 - mu[2]) * isg[2]; t1 = (u1 - mu[3]) * isg[3];
    g.y = __expf(-0.5f * (t0 * t0 + t1 * t1));
    t0 = (u0 - mu[4]) * isg[4]; t1 = (u1 - mu[5]) * isg[5];
    g.z = __expf(-0.5f * (t0 * t0 + t1 * t1));
    g.w = 0.f;
    return g;
}

// all 4 layers' 64x64 gauss tables
__global__ __launch_bounds__(256) void k_tables(const float* __restrict__ mu,
                                                const float* __restrict__ isg,
                                                const float* __restrict__ ppw,
                                                const float* __restrict__ ppb,
                                                float4* __restrict__ tbl) {
    int i = blockIdx.x * 256 + threadIdx.x;  // 4*4096
    int l = i >> 12;
    int idx = i & 4095;
    tbl[i] = gauss_direct(idx >> 6, idx & 63, mu + l * 6, isg + l * 6,
                          ppw + l * 4, ppb + l * 2);
}

// ---------------- weight transpose: wt4[l][q*12+m][cp] = {w(q*48+4m+i, cp)} ----------------
// w(j, cp) = fc_w[l][(j>>6)*64 + cp][j&63]; per-layer 48*64 = 3072 float4 entries
__global__ __launch_bounds__(256) void k_wprep(const float* __restrict__ fcw,
                                               float4* __restrict__ wt4) {
    int i = blockIdx.x * 256 + threadIdx.x;   // 4 * 3072 = 12288
    if (i >= 4 * 48 * 64) return;
    int l = i / 3072;         // layer
    int r = i - l * 3072;     // qm*64 + cp
    int qm = r >> 6;          // q*12+m  (0..47)
    int cp = r & 63;
    int j0 = qm * 4;          // k-index base
    const float* base = fcw + (size_t)l * KOUT * HID;
    float4 v;
    v.x = base[((j0 + 0) >> 6) * 4096 + cp * 64 + ((j0 + 0) & 63)];
    v.y = base[((j0 + 1) >> 6) * 4096 + cp * 64 + ((j0 + 1) & 63)];
    v.z = base[((j0 + 2) >> 6) * 4096 + cp * 64 + ((j0 + 2) & 63)];
    v.w = base[((j0 + 3) >> 6) * 4096 + cp * 64 + ((j0 + 3) & 63)];
    wt4[i] = v;
}

// ---------------- pull aggregation: one wave per node (r13 structure) ----------------
// L0: exact f32 emb gather. Layers 1-3: bf16 mirror h2 (half the gather bytes).
template <bool L0>
__global__ __launch_bounds__(256) void k_pull(const int* __restrict__ rowptr,
                                              const int2* __restrict__ csr_e,
                                              const float4* __restrict__ tbl,
                                              const unsigned short* __restrict__ h2,
                                              const int* __restrict__ h_idx,
                                              const float* __restrict__ emb,
                                              const int* __restrict__ deg,
                                              const float* __restrict__ mu,
                                              const float* __restrict__ isg,
                                              const float* __restrict__ ppw,
                                              const float* __restrict__ ppb,
                                              float* __restrict__ a3) {
    int n = blockIdx.x * 4 + (threadIdx.x >> 6);
    n = __builtin_amdgcn_readfirstlane(n);
    if (n >= N_NODES) return;
    int lane = threadIdx.x & 63;
    int beg = rowptr[n];
    int end = rowptr[n + 1];
    int dd = end - beg;
    float a0 = 0.f, a1 = 0.f, a2 = 0.f;

    auto getg = [&](int2 r) -> float4 {
        if (__builtin_expect(r.y >= 0, 1)) return tbl[r.y];
        return gauss_direct(deg[r.x], dd, mu, isg, ppw, ppb);
    };
    auto geth = [&](int s) -> float {
        if (L0) return emb[h_idx[s] * HID + lane];
        return __uint_as_float((unsigned)h2[(size_t)s * HID + lane] << 16);
    };

    int p = beg;
    for (; p + 8 <= end; p += 8) {
        int2 r[8];
#pragma unroll
        for (int u = 0; u < 8; ++u) r[u] = csr_e[p + u];
        float hv[8];
#pragma unroll
        for (int u = 0; u < 8; ++u) hv[u] = geth(r[u].x);
#pragma unroll
        for (int u = 0; u < 8; ++u) {
            float4 g = getg(r[u]);
            a0 = fmaf(g.x, hv[u], a0); a1 = fmaf(g.y, hv[u], a1); a2 = fmaf(g.z, hv[u], a2);
        }
    }
    for (; p + 4 <= end; p += 4) {
        int2 r0 = csr_e[p], r1 = csr_e[p + 1], r2 = csr_e[p + 2], r3 = csr_e[p + 3];
        float h0 = geth(r0.x), h1 = geth(r1.x), h2v = geth(r2.x), h3 = geth(r3.x);
        float4 g0 = getg(r0), g1 = getg(r1), g2 = getg(r2), g3 = getg(r3);
        a0 = fmaf(g0.x, h0, a0); a1 = fmaf(g0.y, h0, a1); a2 = fmaf(g0.z, h0, a2);
        a0 = fmaf(g1.x, h1, a0); a1 = fmaf(g1.y, h1, a1); a2 = fmaf(g1.z, h1, a2);
        a0 = fmaf(g2.x, h2v, a0); a1 = fmaf(g2.y, h2v, a1); a2 = fmaf(g2.z, h2v, a2);
        a0 = fmaf(g3.x, h3, a0); a1 = fmaf(g3.y, h3, a1); a2 = fmaf(g3.z, h3, a2);
    }
    for (; p < end; ++p) {
        int2 r0 = csr_e[p];
        float h0 = geth(r0.x);
        float4 g0 = getg(r0);
        a0 = fmaf(g0.x, h0, a0); a1 = fmaf(g0.y, h0, a1); a2 = fmaf(g0.z, h0, a2);
    }
    float* out = a3 + (size_t)n * KOUT + lane;
    out[0] = a0;
    out[64] = a1;
    out[128] = a2;
}

// ---------------- fc2: weights (pre-transposed) coalesced, small batch, grid-stride ----------------
#define FC2_B 8
#define FC2_GRID 2048
__global__ __launch_bounds__(256) void k_fc2(const float* __restrict__ a3,
                                             const float4* __restrict__ wt4,
                                             float* __restrict__ agg,
                                             float* __restrict__ bnpart) {
    __shared__ float4 sa4[FC2_B][49];   // 6.3 KB
    __shared__ float sp[4][FC2_B][65];  // 8.3 KB
    __shared__ float bnp[4][128];       // 2 KB
    int t = threadIdx.x;
    int cp = t & 63;
    int q = t >> 6;
    float4 wv[12];
#pragma unroll
    for (int m = 0; m < 12; ++m) wv[m] = wt4[(q * 12 + m) * 64 + cp];
    float bnS = 0.f, bnQ = 0.f;
    const float4* a3v = (const float4*)a3;
    for (int base = blockIdx.x * FC2_B; base < N_NODES; base += FC2_GRID * FC2_B) {
        __syncthreads();  // protect sa4/sp from previous batch
        for (int ii = t; ii < FC2_B * 48; ii += 256) {
            int nn = ii / 48, jj = ii - nn * 48;
            int node = base + nn;
            sa4[nn][jj] = (node < N_NODES) ? a3v[(size_t)node * 48 + jj]
                                           : make_float4(0.f, 0.f, 0.f, 0.f);
        }
        __syncthreads();
        float acc[FC2_B];
#pragma unroll
        for (int nn = 0; nn < FC2_B; ++nn) acc[nn] = 0.f;
#pragma unroll
        for (int m = 0; m < 12; ++m) {
            float4 wm = wv[m];
#pragma unroll
            for (int nn = 0; nn < FC2_B; ++nn) {
                float4 s4 = sa4[nn][q * 12 + m];
                acc[nn] = fmaf(s4.x, wm.x, acc[nn]);
                acc[nn] = fmaf(s4.y, wm.y, acc[nn]);
                acc[nn] = fmaf(s4.z, wm.z, acc[nn]);
                acc[nn] = fmaf(s4.w, wm.w, acc[nn]);
            }
        }
#pragma unroll
        for (int nn = 0; nn < FC2_B; ++nn) sp[q][nn][cp] = acc[nn];
        __syncthreads();
#pragma unroll
        for (int i = 0; i < 2; ++i) {
            int nn = q + i * 4;
            int node = base + nn;
            if (node < N_NODES) {
                float v = sp[0][nn][cp] + sp[1][nn][cp] + sp[2][nn][cp] + sp[3][nn][cp];
                agg[(size_t)node * HID + cp] = v;
                bnS += v;
                bnQ += v * v;
            }
        }
    }
    __syncthreads();
    bnp[q][cp] = bnS;
    bnp[q][64 + cp] = bnQ;
    __syncthreads();
    if (t < 128) {
        float v = bnp[0][t] + bnp[1][t] + bnp[2][t] + bnp[3][t];
        bnpart[(size_t)t * FC2_GRID + blockIdx.x] = v;
    }
}

// ---------------- deterministic reduce of bnpart -> bnsum (128 blocks, coalesced) ----------------
__global__ __launch_bounds__(256) void k_bnred2(const float* __restrict__ bnpart,
                                                float* __restrict__ bnsum) {
    __shared__ float red[256];
    int c = blockIdx.x;   // channel 0..127
    int t = threadIdx.x;
    float acc = 0.f;
#pragma unroll
    for (int i = 0; i < FC2_GRID / 256; ++i)
        acc += bnpart[(size_t)c * FC2_GRID + i * 256 + t];
    red[t] = acc;
    __syncthreads();
    for (int off = 128; off > 0; off >>= 1) {
        if (t < off) red[t] += red[t + off];
        __syncthreads();
    }
    if (t == 0) bnsum[c] = red[0];
}

// ---------------- BN finalize + apply + residual (float4) -> h (f32) and h2 (bf16) ----------------
template <bool L0>
__global__ __launch_bounds__(256) void k_bnapply(const float4* __restrict__ agg4,
                                                 const float* __restrict__ bnsum,
                                                 const float* __restrict__ bng,
                                                 const float* __restrict__ bnb,
                                                 const int* __restrict__ h_idx,
                                                 const float4* __restrict__ emb4,
                                                 float4* __restrict__ h4,
                                                 unsigned short* __restrict__ h2) {
    __shared__ float ssc[128];
    int t = threadIdx.x;
    if (t < 64) {
        const float invN = 1.0f / (float)N_NODES;
        float mean = bnsum[t] * invN;
        float var = bnsum[64 + t] * invN - mean * mean;
        float scale = bng[t] * rsqrtf(var + EPS);
        ssc[t] = scale;
        ssc[64 + t] = bnb[t] - mean * scale;
    }
    __syncthreads();
    int i = blockIdx.x * 256 + t;  // over N_NODES*16 float4s
    if (i < N_NODES * 16) {
        int c4 = (i & 15) * 4;
        float4 ag = agg4[i];
        float4 hn;
        hn.x = fmaxf(fmaf(ag.x, ssc[c4 + 0], ssc[64 + c4 + 0]), 0.f);
        hn.y = fmaxf(fmaf(ag.y, ssc[c4 + 1], ssc[64 + c4 + 1]), 0.f);
        hn.z = fmaxf(fmaf(ag.z, ssc[c4 + 2], ssc[64 + c4 + 2]), 0.f);
        hn.w = fmaxf(fmaf(ag.w, ssc[c4 + 3], ssc[64 + c4 + 3]), 0.f);
        float4 base;
        if (L0) {
            int n = i >> 4;
            base = emb4[h_idx[n] * 16 + (i & 15)];
        } else {
            base = h4[i];
        }
        base.x += hn.x; base.y += hn.y; base.z += hn.z; base.w += hn.w;
        h4[i] = base;
        uint2 pk;
        pk.x = (unsigned)f2bf(base.x) | ((unsigned)f2bf(base.y) << 16);
        pk.y = (unsigned)f2bf(base.z) | ((unsigned)f2bf(base.w) << 16);
        *(uint2*)&h2[(size_t)i * 4] = pk;
    }
}

// ---------------- readout: wave per 64-node chunk, run-length accumulate ----------------
__global__ __launch_bounds__(256) void k_readout(const float* __restrict__ h,
                                                 const int* __restrict__ gid,
                                                 float* __restrict__ hg,
                                                 float* __restrict__ cnt) {
    int chunk = blockIdx.x * 4 + (threadIdx.x >> 6);
    int lane = threadIdx.x & 63;
    int n0 = chunk * 64;
    if (n0 >= N_NODES) return;
    int n1 = min(n0 + 64, N_NODES);
    int curg = gid[n0];
    float acc = 0.f;
    int count = 0;
    for (int n = n0; n < n1; ++n) {
        int g = gid[n];
        if (g != curg) {
            atomicAdd(&hg[(size_t)curg * HID + lane], acc);
            if (lane == 0) atomicAdd(&cnt[curg], (float)count);
            curg = g; acc = 0.f; count = 0;
        }
        acc += h[(size_t)n * HID + lane];
        ++count;
    }
    atomicAdd(&hg[(size_t)curg * HID + lane], acc);
    if (lane == 0) atomicAdd(&cnt[curg], (float)count);
}

// ---------------- MLP readout ----------------
__global__ __launch_bounds__(256) void k_mlp(const float* __restrict__ hg,
                                             const float* __restrict__ cnt,
                                             const float* __restrict__ w1, const float* __restrict__ b1,
                                             const float* __restrict__ w2, const float* __restrict__ b2,
                                             const float* __restrict__ w3, const float* __restrict__ b3,
                                             float* __restrict__ out) {
    int g = threadIdx.x;  // 256 threads, single block
    float inv = 1.0f / fmaxf(cnt[g], 1.0f);
    float x[HID];
#pragma unroll
    for (int i = 0; i < HID; ++i) x[i] = hg[(size_t)g * HID + i] * inv;
    float y1[32];
#pragma unroll
    for (int j = 0; j < 32; ++j) {
        float acc = b1[j];
#pragma unroll
        for (int i = 0; i < HID; ++i) acc = fmaf(x[i], w1[j * HID + i], acc);
        y1[j] = fmaxf(acc, 0.f);
    }
    float y2[16];
#pragma unroll
    for (int j = 0; j < 16; ++j) {
        float acc = b2[j];
#pragma unroll
        for (int i = 0; i < 32; ++i) acc = fmaf(y1[i], w2[j * 32 + i], acc);
        y2[j] = fmaxf(acc, 0.f);
    }
    float acc = b3[0];
#pragma unroll
    for (int i = 0; i < 16; ++i) acc = fmaf(y2[i], w3[i], acc);
    out[g] = acc;
}

extern "C" void kernel_launch(void* const* d_in, const int* in_sizes, int n_in,
                              void* d_out, int out_size, void* d_ws, size_t ws_size,
                              hipStream_t stream) {
    const int* h_idx = (const int*)d_in[0];
    const int* src = (const int*)d_in[1];
    const int* dst = (const int*)d_in[2];
    const int* gid = (const int*)d_in[3];
    const float* emb = (const float*)d_in[4];
    const float* fc_w = (const float*)d_in[5];
    const float* mu = (const float*)d_in[6];
    const float* isg = (const float*)d_in[7];
    const float* bng = (const float*)d_in[8];
    const float* bnb = (const float*)d_in[9];
    const float* ppw = (const float*)d_in[10];
    const float* ppb = (const float*)d_in[11];
    const float* w1 = (const float*)d_in[12];
    const float* b1 = (const float*)d_in[13];
    const float* w2 = (const float*)d_in[14];
    const float* b2 = (const float*)d_in[15];
    const float* w3 = (const float*)d_in[16];
    const float* b3 = (const float*)d_in[17];

    char* ws = (char*)d_ws;
    size_t o = 0;
    auto take = [&](size_t bytes) -> char* {
        char* p = ws + o;
        o += (bytes + 255) & ~(size_t)255;
        return p;
    };
    int* deg = (int*)take((size_t)N_NODES * 4);
    int* cursor = (int*)take((size_t)N_NODES * 4);
    int* rowptr = (int*)take((size_t)(N_NODES + 1) * 4);
    int* blocksum = (int*)take((size_t)NB1 * 4);
    int* blockoff = (int*)take((size_t)NB1 * 4);
    int2* csr_e = (int2*)take((size_t)N_EDGES * 8);
    float4* tbl = (float4*)take((size_t)4 * 4096 * 16);
    float4* wt4 = (float4*)take((size_t)4 * 48 * 64 * 16);  // 192 KB
    float* h = (float*)take((size_t)N_NODES * HID * 4);
    unsigned short* h2 = (unsigned short*)take((size_t)N_NODES * HID * 2);  // bf16 mirror
    float* a3 = (float*)take((size_t)N_NODES * KOUT * 4);
    float* agg = (float*)take((size_t)N_NODES * HID * 4);
    float* bnpart = (float*)take((size_t)128 * FC2_GRID * 4);  // 1 MB channel-major
    float* bnsum = (float*)take(128 * 4);
    float* hg = (float*)take((size_t)N_GRAPHS * HID * 4);
    float* cnt = (float*)take((size_t)N_GRAPHS * 4);

    hipMemsetAsync(deg, 0, (size_t)N_NODES * 4, stream);
    hipMemsetAsync(hg, 0, (size_t)(N_GRAPHS * HID + N_GRAPHS) * 4, stream);

    k_deg<<<(N_EDGES + 255) / 256, 256, 0, stream>>>(dst, deg);
    k_scan1<<<NB1, 256, 0, stream>>>(deg, rowptr, blocksum);
    k_scan2<<<1, 256, 0, stream>>>(blocksum, blockoff);
    k_scan3<<<NB1, 256, 0, stream>>>(rowptr, blockoff, cursor);
    k_scatter<<<(N_EDGES + 255) / 256, 256, 0, stream>>>(src, dst, deg, cursor, csr_e);
    k_tables<<<(4 * 4096) / 256, 256, 0, stream>>>(mu, isg, ppw, ppb, tbl);
    k_wprep<<<(4 * 48 * 64 + 255) / 256, 256, 0, stream>>>(fc_w, wt4);

    for (int l = 0; l < 4; ++l) {
        const float* mul = mu + l * 6;
        const float* isgl = isg + l * 6;
        const float* ppwl = ppw + l * 4;
        const float* ppbl = ppb + l * 2;
        const float4* tbll = tbl + (size_t)l * 4096;
        if (l == 0)
            k_pull<true><<<(N_NODES + 3) / 4, 256, 0, stream>>>(rowptr, csr_e, tbll, h2,
                h_idx, emb, deg, mul, isgl, ppwl, ppbl, a3);
        else
            k_pull<false><<<(N_NODES + 3) / 4, 256, 0, stream>>>(rowptr, csr_e, tbll, h2,
                h_idx, emb, deg, mul, isgl, ppwl, ppbl, a3);
        k_fc2<<<FC2_GRID, 256, 0, stream>>>(
            a3, wt4 + (size_t)l * 48 * 64, agg, bnpart);
        k_bnred2<<<128, 256, 0, stream>>>(bnpart, bnsum);
        if (l == 0)
            k_bnapply<true><<<(N_NODES * 16 + 255) / 256, 256, 0, stream>>>(
                (const float4*)agg, bnsum, bng + l * 64, bnb + l * 64,
                h_idx, (const float4*)emb, (float4*)h, h2);
        else
            k_bnapply<false><<<(N_NODES * 16 + 255) / 256, 256, 0, stream>>>(
                (const float4*)agg, bnsum, bng + l * 64, bnb + l * 64,
                h_idx, (const float4*)emb, (float4*)h, h2);
    }

    k_readout<<<(N_NODES / 64 + 3) / 4 + 1, 256, 0, stream>>>(h, gid, hg, cnt);
    k_mlp<<<1, 256, 0, stream>>>(hg, cnt, w1, b1, w2, b2, w3, b3, (float*)d_out);
}

// Round 19
// 414.777 us; speedup vs baseline: 1.2585x; 1.0643x over previous
//
#include <hip/hip_runtime.h>
#include <hip/hip_bf16.h>

#define N_NODES 50000
#define N_EDGES 800000
#define N_GRAPHS 256
#define HID 64
#define KOUT 192   // K * OUT
#define EPS 1e-5f
#define NB1 196    // ceil(N_NODES / 256)

__device__ __forceinline__ unsigned short f2bf(float x) {
    unsigned u = __float_as_uint(x);
    unsigned r = (u + 0x7FFFu + ((u >> 16) & 1u)) >> 16;  // round-nearest-even
    return (unsigned short)r;
}

// ---------------- degree ----------------
__global__ void k_deg(const int* __restrict__ dst, int* __restrict__ deg) {
    int i = blockIdx.x * blockDim.x + threadIdx.x;
    if (i < N_EDGES) atomicAdd(&deg[dst[i]], 1);
}

// ---------------- hierarchical exclusive scan of deg -> rowptr ----------------
__global__ __launch_bounds__(256) void k_scan1(const int* __restrict__ deg,
                                               int* __restrict__ rowptr,
                                               int* __restrict__ blocksum) {
    __shared__ int sc[256];
    int t = threadIdx.x;
    int i = blockIdx.x * 256 + t;
    int v = (i < N_NODES) ? deg[i] : 0;
    sc[t] = v;
    __syncthreads();
    for (int off = 1; off < 256; off <<= 1) {
        int u = (t >= off) ? sc[t - off] : 0;
        __syncthreads();
        sc[t] += u;
        __syncthreads();
    }
    if (i < N_NODES) rowptr[i] = sc[t] - v;  // exclusive local prefix
    if (t == 255) blocksum[blockIdx.x] = sc[255];
}

__global__ __launch_bounds__(256) void k_scan2(const int* __restrict__ blocksum,
                                               int* __restrict__ blockoff) {
    __shared__ int sc[256];
    int t = threadIdx.x;
    int v = (t < NB1) ? blocksum[t] : 0;
    sc[t] = v;
    __syncthreads();
    for (int off = 1; off < 256; off <<= 1) {
        int u = (t >= off) ? sc[t - off] : 0;
        __syncthreads();
        sc[t] += u;
        __syncthreads();
    }
    if (t < NB1) blockoff[t] = sc[t] - v;
}

// rowptr[i] += blockoff[i>>8]; cursor[i] = rowptr[i]; rowptr[N]=E
__global__ __launch_bounds__(256) void k_scan3(int* __restrict__ rowptr,
                                               const int* __restrict__ blockoff,
                                               int* __restrict__ cursor) {
    int i = blockIdx.x * 256 + threadIdx.x;
    if (i < N_NODES) {
        int r = rowptr[i] + blockoff[i >> 8];
        rowptr[i] = r;
        cursor[i] = r;
    }
    if (i == 0) rowptr[N_NODES] = N_EDGES;
}

// ---------------- scatter edges into CSR (by dst), packed 4B: src | (gidx<<16) ----------------
// src < 65536; gidx = ds*64+dd (0..4095) or 0xFFFF sentinel for deg>=64.
__global__ void k_scatter(const int* __restrict__ src, const int* __restrict__ dst,
                          const int* __restrict__ deg, int* __restrict__ cursor,
                          unsigned* __restrict__ csr_e) {
    int e = blockIdx.x * blockDim.x + threadIdx.x;
    if (e >= N_EDGES) return;
    int s = src[e], d = dst[e];
    int p = atomicAdd(&cursor[d], 1);
    int ds = deg[s], dd = deg[d];
    unsigned gi = (ds < 64 && dd < 64) ? (unsigned)(ds * 64 + dd) : 0xFFFFu;
    csr_e[p] = (unsigned)s | (gi << 16);
}

// ---------------- gaussian from degrees (shared by table + fallback) ----------------
__device__ __forceinline__ float4 gauss_direct(int degs, int degd,
                                               const float* __restrict__ mu,
                                               const float* __restrict__ isg,
                                               const float* __restrict__ ppw,
                                               const float* __restrict__ ppb) {
    float p0 = rsqrtf((float)degs + 1.0f);
    float p1 = rsqrtf((float)degd + 1.0f);
    float u0 = tanhf(fmaf(p1, ppw[1], fmaf(p0, ppw[0], ppb[0])));
    float u1 = tanhf(fmaf(p1, ppw[3], fmaf(p0, ppw[2], ppb[1])));
    float4 g;
    float t0, t1;
    t0 = (u0 - mu[0]) * isg[0]; t1 = (u1 - mu[1]) * isg[1];
    g.x = __expf(-0.5f * (t0 * t0 + t1 * t1));
    t0 = (u0 - mu[2]) * isg[2]; t1 = (u1 - mu[3]) * isg[3];
    g.y = __expf(-0.5f * (t0 * t0 + t1 * t1));
    t0 = (u0 - mu[4]) * isg[4]; t1 = (u1 - mu[5]) * isg[5];
    g.z = __expf(-0.5f * (t0 * t0 + t1 * t1));
    g.w = 0.f;
    return g;
}

// all 4 layers' 64x64 gauss tables
__global__ __launch_bounds__(256) void k_tables(const float* __restrict__ mu,
                                                const float* __restrict__ isg,
                                                const float* __restrict__ ppw,
                                                const float* __restrict__ ppb,
                                                float4* __restrict__ tbl) {
    int i = blockIdx.x * 256 + threadIdx.x;  // 4*4096
    int l = i >> 12;
    int idx = i & 4095;
    tbl[i] = gauss_direct(idx >> 6, idx & 63, mu + l * 6, isg + l * 6,
                          ppw + l * 4, ppb + l * 2);
}

// ---------------- weight transpose: wt4[l][q*12+m][cp] = {w(q*48+4m+i, cp)} ----------------
__global__ __launch_bounds__(256) void k_wprep(const float* __restrict__ fcw,
                                               float4* __restrict__ wt4) {
    int i = blockIdx.x * 256 + threadIdx.x;   // 4 * 3072 = 12288
    if (i >= 4 * 48 * 64) return;
    int l = i / 3072;         // layer
    int r = i - l * 3072;     // qm*64 + cp
    int qm = r >> 6;          // q*12+m  (0..47)
    int cp = r & 63;
    int j0 = qm * 4;          // k-index base
    const float* base = fcw + (size_t)l * KOUT * HID;
    float4 v;
    v.x = base[((j0 + 0) >> 6) * 4096 + cp * 64 + ((j0 + 0) & 63)];
    v.y = base[((j0 + 1) >> 6) * 4096 + cp * 64 + ((j0 + 1) & 63)];
    v.z = base[((j0 + 2) >> 6) * 4096 + cp * 64 + ((j0 + 2) & 63)];
    v.w = base[((j0 + 3) >> 6) * 4096 + cp * 64 + ((j0 + 3) & 63)];
    wt4[i] = v;
}

// ---------------- pull aggregation: one wave per node (r13 structure, packed csr) ----------------
// L0: exact f32 emb gather. Layers 1-3: bf16 mirror h2 (half the gather bytes).
template <bool L0>
__global__ __launch_bounds__(256) void k_pull(const int* __restrict__ rowptr,
                                              const unsigned* __restrict__ csr_e,
                                              const float4* __restrict__ tbl,
                                              const unsigned short* __restrict__ h2,
                                              const int* __restrict__ h_idx,
                                              const float* __restrict__ emb,
                                              const int* __restrict__ deg,
                                              const float* __restrict__ mu,
                                              const float* __restrict__ isg,
                                              const float* __restrict__ ppw,
                                              const float* __restrict__ ppb,
                                              float* __restrict__ a3) {
    int n = blockIdx.x * 4 + (threadIdx.x >> 6);
    n = __builtin_amdgcn_readfirstlane(n);
    if (n >= N_NODES) return;
    int lane = threadIdx.x & 63;
    int beg = rowptr[n];
    int end = rowptr[n + 1];
    int dd = end - beg;
    float a0 = 0.f, a1 = 0.f, a2 = 0.f;

    auto getg = [&](unsigned r) -> float4 {
        unsigned gi = r >> 16;
        if (__builtin_expect(gi != 0xFFFFu, 1)) return tbl[gi];
        return gauss_direct(deg[r & 0xFFFFu], dd, mu, isg, ppw, ppb);
    };
    auto geth = [&](unsigned r) -> float {
        int s = (int)(r & 0xFFFFu);
        if (L0) return emb[h_idx[s] * HID + lane];
        return __uint_as_float((unsigned)h2[(size_t)s * HID + lane] << 16);
    };

    int p = beg;
    for (; p + 8 <= end; p += 8) {
        unsigned r[8];
#pragma unroll
        for (int u = 0; u < 8; ++u) r[u] = csr_e[p + u];
        float hv[8];
#pragma unroll
        for (int u = 0; u < 8; ++u) hv[u] = geth(r[u]);
#pragma unroll
        for (int u = 0; u < 8; ++u) {
            float4 g = getg(r[u]);
            a0 = fmaf(g.x, hv[u], a0); a1 = fmaf(g.y, hv[u], a1); a2 = fmaf(g.z, hv[u], a2);
        }
    }
    for (; p + 4 <= end; p += 4) {
        unsigned r0 = csr_e[p], r1 = csr_e[p + 1], r2 = csr_e[p + 2], r3 = csr_e[p + 3];
        float h0 = geth(r0), h1 = geth(r1), h2v = geth(r2), h3 = geth(r3);
        float4 g0 = getg(r0), g1 = getg(r1), g2 = getg(r2), g3 = getg(r3);
        a0 = fmaf(g0.x, h0, a0); a1 = fmaf(g0.y, h0, a1); a2 = fmaf(g0.z, h0, a2);
        a0 = fmaf(g1.x, h1, a0); a1 = fmaf(g1.y, h1, a1); a2 = fmaf(g1.z, h1, a2);
        a0 = fmaf(g2.x, h2v, a0); a1 = fmaf(g2.y, h2v, a1); a2 = fmaf(g2.z, h2v, a2);
        a0 = fmaf(g3.x, h3, a0); a1 = fmaf(g3.y, h3, a1); a2 = fmaf(g3.z, h3, a2);
    }
    for (; p < end; ++p) {
        unsigned r0 = csr_e[p];
        float h0 = geth(r0);
        float4 g0 = getg(r0);
        a0 = fmaf(g0.x, h0, a0); a1 = fmaf(g0.y, h0, a1); a2 = fmaf(g0.z, h0, a2);
    }
    float* out = a3 + (size_t)n * KOUT + lane;
    out[0] = a0;
    out[64] = a1;
    out[128] = a2;
}

// ---------------- fc2: weights (pre-transposed) coalesced, small batch, grid-stride ----------------
#define FC2_B 8
#define FC2_GRID 2048
__global__ __launch_bounds__(256) void k_fc2(const float* __restrict__ a3,
                                             const float4* __restrict__ wt4,
                                             float* __restrict__ agg,
                                             float* __restrict__ bnpart) {
    __shared__ float4 sa4[FC2_B][49];   // 6.3 KB
    __shared__ float sp[4][FC2_B][65];  // 8.3 KB
    __shared__ float bnp[4][128];       // 2 KB
    int t = threadIdx.x;
    int cp = t & 63;
    int q = t >> 6;
    float4 wv[12];
#pragma unroll
    for (int m = 0; m < 12; ++m) wv[m] = wt4[(q * 12 + m) * 64 + cp];
    float bnS = 0.f, bnQ = 0.f;
    const float4* a3v = (const float4*)a3;
    for (int base = blockIdx.x * FC2_B; base < N_NODES; base += FC2_GRID * FC2_B) {
        __syncthreads();  // protect sa4/sp from previous batch
        for (int ii = t; ii < FC2_B * 48; ii += 256) {
            int nn = ii / 48, jj = ii - nn * 48;
            int node = base + nn;
            sa4[nn][jj] = (node < N_NODES) ? a3v[(size_t)node * 48 + jj]
                                           : make_float4(0.f, 0.f, 0.f, 0.f);
        }
        __syncthreads();
        float acc[FC2_B];
#pragma unroll
        for (int nn = 0; nn < FC2_B; ++nn) acc[nn] = 0.f;
#pragma unroll
        for (int m = 0; m < 12; ++m) {
            float4 wm = wv[m];
#pragma unroll
            for (int nn = 0; nn < FC2_B; ++nn) {
                float4 s4 = sa4[nn][q * 12 + m];
                acc[nn] = fmaf(s4.x, wm.x, acc[nn]);
                acc[nn] = fmaf(s4.y, wm.y, acc[nn]);
                acc[nn] = fmaf(s4.z, wm.z, acc[nn]);
                acc[nn] = fmaf(s4.w, wm.w, acc[nn]);
            }
        }
#pragma unroll
        for (int nn = 0; nn < FC2_B; ++nn) sp[q][nn][cp] = acc[nn];
        __syncthreads();
#pragma unroll
        for (int i = 0; i < 2; ++i) {
            int nn = q + i * 4;
            int node = base + nn;
            if (node < N_NODES) {
                float v = sp[0][nn][cp] + sp[1][nn][cp] + sp[2][nn][cp] + sp[3][nn][cp];
                agg[(size_t)node * HID + cp] = v;
                bnS += v;
                bnQ += v * v;
            }
        }
    }
    __syncthreads();
    bnp[q][cp] = bnS;
    bnp[q][64 + cp] = bnQ;
    __syncthreads();
    if (t < 128) {
        float v = bnp[0][t] + bnp[1][t] + bnp[2][t] + bnp[3][t];
        bnpart[(size_t)t * FC2_GRID + blockIdx.x] = v;
    }
}

// ---------------- deterministic reduce of bnpart -> bnsum (128 blocks, coalesced) ----------------
__global__ __launch_bounds__(256) void k_bnred2(const float* __restrict__ bnpart,
                                                float* __restrict__ bnsum) {
    __shared__ float red[256];
    int c = blockIdx.x;   // channel 0..127
    int t = threadIdx.x;
    float acc = 0.f;
#pragma unroll
    for (int i = 0; i < FC2_GRID / 256; ++i)
        acc += bnpart[(size_t)c * FC2_GRID + i * 256 + t];
    red[t] = acc;
    __syncthreads();
    for (int off = 128; off > 0; off >>= 1) {
        if (t < off) red[t] += red[t + off];
        __syncthreads();
    }
    if (t == 0) bnsum[c] = red[0];
}

// ---------------- BN finalize + apply + residual (float4) -> h (f32) and h2 (bf16) ----------------
template <bool L0>
__global__ __launch_bounds__(256) void k_bnapply(const float4* __restrict__ agg4,
                                                 const float* __restrict__ bnsum,
                                                 const float* __restrict__ bng,
                                                 const float* __restrict__ bnb,
                                                 const int* __restrict__ h_idx,
                                                 const float4* __restrict__ emb4,
                                                 float4* __restrict__ h4,
                                                 unsigned short* __restrict__ h2) {
    __shared__ float ssc[128];
    int t = threadIdx.x;
    if (t < 64) {
        const float invN = 1.0f / (float)N_NODES;
        float mean = bnsum[t] * invN;
        float var = bnsum[64 + t] * invN - mean * mean;
        float scale = bng[t] * rsqrtf(var + EPS);
        ssc[t] = scale;
        ssc[64 + t] = bnb[t] - mean * scale;
    }
    __syncthreads();
    int i = blockIdx.x * 256 + t;  // over N_NODES*16 float4s
    if (i < N_NODES * 16) {
        int c4 = (i & 15) * 4;
        float4 ag = agg4[i];
        float4 hn;
        hn.x = fmaxf(fmaf(ag.x, ssc[c4 + 0], ssc[64 + c4 + 0]), 0.f);
        hn.y = fmaxf(fmaf(ag.y, ssc[c4 + 1], ssc[64 + c4 + 1]), 0.f);
        hn.z = fmaxf(fmaf(ag.z, ssc[c4 + 2], ssc[64 + c4 + 2]), 0.f);
        hn.w = fmaxf(fmaf(ag.w, ssc[c4 + 3], ssc[64 + c4 + 3]), 0.f);
        float4 base;
        if (L0) {
            int n = i >> 4;
            base = emb4[h_idx[n] * 16 + (i & 15)];
        } else {
            base = h4[i];
        }
        base.x += hn.x; base.y += hn.y; base.z += hn.z; base.w += hn.w;
        h4[i] = base;
        uint2 pk;
        pk.x = (unsigned)f2bf(base.x) | ((unsigned)f2bf(base.y) << 16);
        pk.y = (unsigned)f2bf(base.z) | ((unsigned)f2bf(base.w) << 16);
        *(uint2*)&h2[(size_t)i * 4] = pk;
    }
}

// ---------------- readout: wave per 64-node chunk, run-length accumulate ----------------
__global__ __launch_bounds__(256) void k_readout(const float* __restrict__ h,
                                                 const int* __restrict__ gid,
                                                 float* __restrict__ hg,
                                                 float* __restrict__ cnt) {
    int chunk = blockIdx.x * 4 + (threadIdx.x >> 6);
    int lane = threadIdx.x & 63;
    int n0 = chunk * 64;
    if (n0 >= N_NODES) return;
    int n1 = min(n0 + 64, N_NODES);
    int curg = gid[n0];
    float acc = 0.f;
    int count = 0;
    for (int n = n0; n < n1; ++n) {
        int g = gid[n];
        if (g != curg) {
            atomicAdd(&hg[(size_t)curg * HID + lane], acc);
            if (lane == 0) atomicAdd(&cnt[curg], (float)count);
            curg = g; acc = 0.f; count = 0;
        }
        acc += h[(size_t)n * HID + lane];
        ++count;
    }
    atomicAdd(&hg[(size_t)curg * HID + lane], acc);
    if (lane == 0) atomicAdd(&cnt[curg], (float)count);
}

// ---------------- MLP readout ----------------
__global__ __launch_bounds__(256) void k_mlp(const float* __restrict__ hg,
                                             const float* __restrict__ cnt,
                                             const float* __restrict__ w1, const float* __restrict__ b1,
                                             const float* __restrict__ w2, const float* __restrict__ b2,
                                             const float* __restrict__ w3, const float* __restrict__ b3,
                                             float* __restrict__ out) {
    int g = threadIdx.x;  // 256 threads, single block
    float inv = 1.0f / fmaxf(cnt[g], 1.0f);
    float x[HID];
#pragma unroll
    for (int i = 0; i < HID; ++i) x[i] = hg[(size_t)g * HID + i] * inv;
    float y1[32];
#pragma unroll
    for (int j = 0; j < 32; ++j) {
        float acc = b1[j];
#pragma unroll
        for (int i = 0; i < HID; ++i) acc = fmaf(x[i], w1[j * HID + i], acc);
        y1[j] = fmaxf(acc, 0.f);
    }
    float y2[16];
#pragma unroll
    for (int j = 0; j < 16; ++j) {
        float acc = b2[j];
#pragma unroll
        for (int i = 0; i < 32; ++i) acc = fmaf(y1[i], w2[j * 32 + i], acc);
        y2[j] = fmaxf(acc, 0.f);
    }
    float acc = b3[0];
#pragma unroll
    for (int i = 0; i < 16; ++i) acc = fmaf(y2[i], w3[i], acc);
    out[g] = acc;
}

extern "C" void kernel_launch(void* const* d_in, const int* in_sizes, int n_in,
                              void* d_out, int out_size, void* d_ws, size_t ws_size,
                              hipStream_t stream) {
    const int* h_idx = (const int*)d_in[0];
    const int* src = (const int*)d_in[1];
    const int* dst = (const int*)d_in[2];
    const int* gid = (const int*)d_in[3];
    const float* emb = (const float*)d_in[4];
    const float* fc_w = (const float*)d_in[5];
    const float* mu = (const float*)d_in[6];
    const float* isg = (const float*)d_in[7];
    const float* bng = (const float*)d_in[8];
    const float* bnb = (const float*)d_in[9];
    const float* ppw = (const float*)d_in[10];
    const float* ppb = (const float*)d_in[11];
    const float* w1 = (const float*)d_in[12];
    const float* b1 = (const float*)d_in[13];
    const float* w2 = (const float*)d_in[14];
    const float* b2 = (const float*)d_in[15];
    const float* w3 = (const float*)d_in[16];
    const float* b3 = (const float*)d_in[17];

    char* ws = (char*)d_ws;
    size_t o = 0;
    auto take = [&](size_t bytes) -> char* {
        char* p = ws + o;
        o += (bytes + 255) & ~(size_t)255;
        return p;
    };
    int* deg = (int*)take((size_t)N_NODES * 4);
    int* cursor = (int*)take((size_t)N_NODES * 4);
    int* rowptr = (int*)take((size_t)(N_NODES + 1) * 4);
    int* blocksum = (int*)take((size_t)NB1 * 4);
    int* blockoff = (int*)take((size_t)NB1 * 4);
    unsigned* csr_e = (unsigned*)take((size_t)N_EDGES * 4);
    float4* tbl = (float4*)take((size_t)4 * 4096 * 16);
    float4* wt4 = (float4*)take((size_t)4 * 48 * 64 * 16);  // 192 KB
    float* h = (float*)take((size_t)N_NODES * HID * 4);
    unsigned short* h2 = (unsigned short*)take((size_t)N_NODES * HID * 2);  // bf16 mirror
    float* a3 = (float*)take((size_t)N_NODES * KOUT * 4);
    float* agg = (float*)take((size_t)N_NODES * HID * 4);
    float* bnpart = (float*)take((size_t)128 * FC2_GRID * 4);  // 1 MB channel-major
    float* bnsum = (float*)take(128 * 4);
    float* hg = (float*)take((size_t)N_GRAPHS * HID * 4);
    float* cnt = (float*)take((size_t)N_GRAPHS * 4);

    hipMemsetAsync(deg, 0, (size_t)N_NODES * 4, stream);
    hipMemsetAsync(hg, 0, (size_t)(N_GRAPHS * HID + N_GRAPHS) * 4, stream);

    k_deg<<<(N_EDGES + 255) / 256, 256, 0, stream>>>(dst, deg);
    k_scan1<<<NB1, 256, 0, stream>>>(deg, rowptr, blocksum);
    k_scan2<<<1, 256, 0, stream>>>(blocksum, blockoff);
    k_scan3<<<NB1, 256, 0, stream>>>(rowptr, blockoff, cursor);
    k_scatter<<<(N_EDGES + 255) / 256, 256, 0, stream>>>(src, dst, deg, cursor, csr_e);
    k_tables<<<(4 * 4096) / 256, 256, 0, stream>>>(mu, isg, ppw, ppb, tbl);
    k_wprep<<<(4 * 48 * 64 + 255) / 256, 256, 0, stream>>>(fc_w, wt4);

    for (int l = 0; l < 4; ++l) {
        const float* mul = mu + l * 6;
        const float* isgl = isg + l * 6;
        const float* ppwl = ppw + l * 4;
        const float* ppbl = ppb + l * 2;
        const float4* tbll = tbl + (size_t)l * 4096;
        if (l == 0)
            k_pull<true><<<(N_NODES + 3) / 4, 256, 0, stream>>>(rowptr, csr_e, tbll, h2,
                h_idx, emb, deg, mul, isgl, ppwl, ppbl, a3);
        else
            k_pull<false><<<(N_NODES + 3) / 4, 256, 0, stream>>>(rowptr, csr_e, tbll, h2,
                h_idx, emb, deg, mul, isgl, ppwl, ppbl, a3);
        k_fc2<<<FC2_GRID, 256, 0, stream>>>(
            a3, wt4 + (size_t)l * 48 * 64, agg, bnpart);
        k_bnred2<<<128, 256, 0, stream>>>(bnpart, bnsum);
        if (l == 0)
            k_bnapply<true><<<(N_NODES * 16 + 255) / 256, 256, 0, stream>>>(
                (const float4*)agg, bnsum, bng + l * 64, bnb + l * 64,
                h_idx, (const float4*)emb, (float4*)h, h2);
        else
            k_bnapply<false><<<(N_NODES * 16 + 255) / 256, 256, 0, stream>>>(
                (const float4*)agg, bnsum, bng + l * 64, bnb + l * 64,
                h_idx, (const float4*)emb, (float4*)h, h2);
    }

    k_readout<<<(N_NODES / 64 + 3) / 4 + 1, 256, 0, stream>>>(h, gid, hg, cnt);
    k_mlp<<<1, 256, 0, stream>>>(hg, cnt, w1, b1, w2, b2, w3, b3, (float*)d_out);
}

// Round 20
// 411.509 us; speedup vs baseline: 1.2685x; 1.0079x over previous
//
#include <hip/hip_runtime.h>
#include <hip/hip_bf16.h>

#define N_NODES 50000
#define N_EDGES 800000
#define N_GRAPHS 256
#define HID 64
#define KOUT 192   // K * OUT
#define EPS 1e-5f
#define NB1 196    // ceil(N_NODES / 256)

__device__ __forceinline__ unsigned short f2bf(float x) {
    unsigned u = __float_as_uint(x);
    unsigned r = (u + 0x7FFFu + ((u >> 16) & 1u)) >> 16;  // round-nearest-even
    return (unsigned short)r;
}

// ---------------- degree ----------------
__global__ void k_deg(const int* __restrict__ dst, int* __restrict__ deg) {
    int i = blockIdx.x * blockDim.x + threadIdx.x;
    if (i < N_EDGES) atomicAdd(&deg[dst[i]], 1);
}

// ---------------- hierarchical exclusive scan of deg -> rowptr ----------------
__global__ __launch_bounds__(256) void k_scan1(const int* __restrict__ deg,
                                               int* __restrict__ rowptr,
                                               int* __restrict__ blocksum) {
    __shared__ int sc[256];
    int t = threadIdx.x;
    int i = blockIdx.x * 256 + t;
    int v = (i < N_NODES) ? deg[i] : 0;
    sc[t] = v;
    __syncthreads();
    for (int off = 1; off < 256; off <<= 1) {
        int u = (t >= off) ? sc[t - off] : 0;
        __syncthreads();
        sc[t] += u;
        __syncthreads();
    }
    if (i < N_NODES) rowptr[i] = sc[t] - v;  // exclusive local prefix
    if (t == 255) blocksum[blockIdx.x] = sc[255];
}

__global__ __launch_bounds__(256) void k_scan2(const int* __restrict__ blocksum,
                                               int* __restrict__ blockoff) {
    __shared__ int sc[256];
    int t = threadIdx.x;
    int v = (t < NB1) ? blocksum[t] : 0;
    sc[t] = v;
    __syncthreads();
    for (int off = 1; off < 256; off <<= 1) {
        int u = (t >= off) ? sc[t - off] : 0;
        __syncthreads();
        sc[t] += u;
        __syncthreads();
    }
    if (t < NB1) blockoff[t] = sc[t] - v;
}

// rowptr[i] += blockoff[i>>8]; cursor[i] = rowptr[i]; rowptr[N]=E
__global__ __launch_bounds__(256) void k_scan3(int* __restrict__ rowptr,
                                               const int* __restrict__ blockoff,
                                               int* __restrict__ cursor) {
    int i = blockIdx.x * 256 + threadIdx.x;
    if (i < N_NODES) {
        int r = rowptr[i] + blockoff[i >> 8];
        rowptr[i] = r;
        cursor[i] = r;
    }
    if (i == 0) rowptr[N_NODES] = N_EDGES;
}

// ---------------- scatter edges into CSR (by dst), packed 4B: src | (gidx<<16) ----------------
// src < 65536; gidx = ds*64+dd (0..4095) or 0xFFFF sentinel for deg>=64.
__global__ void k_scatter(const int* __restrict__ src, const int* __restrict__ dst,
                          const int* __restrict__ deg, int* __restrict__ cursor,
                          unsigned* __restrict__ csr_e) {
    int e = blockIdx.x * blockDim.x + threadIdx.x;
    if (e >= N_EDGES) return;
    int s = src[e], d = dst[e];
    int p = atomicAdd(&cursor[d], 1);
    int ds = deg[s], dd = deg[d];
    unsigned gi = (ds < 64 && dd < 64) ? (unsigned)(ds * 64 + dd) : 0xFFFFu;
    csr_e[p] = (unsigned)s | (gi << 16);
}

// ---------------- gaussian from degrees (shared by table + fallback) ----------------
__device__ __forceinline__ float4 gauss_direct(int degs, int degd,
                                               const float* __restrict__ mu,
                                               const float* __restrict__ isg,
                                               const float* __restrict__ ppw,
                                               const float* __restrict__ ppb) {
    float p0 = rsqrtf((float)degs + 1.0f);
    float p1 = rsqrtf((float)degd + 1.0f);
    float u0 = tanhf(fmaf(p1, ppw[1], fmaf(p0, ppw[0], ppb[0])));
    float u1 = tanhf(fmaf(p1, ppw[3], fmaf(p0, ppw[2], ppb[1])));
    float4 g;
    float t0, t1;
    t0 = (u0 - mu[0]) * isg[0]; t1 = (u1 - mu[1]) * isg[1];
    g.x = __expf(-0.5f * (t0 * t0 + t1 * t1));
    t0 = (u0 - mu[2]) * isg[2]; t1 = (u1 - mu[3]) * isg[3];
    g.y = __expf(-0.5f * (t0 * t0 + t1 * t1));
    t0 = (u0 - mu[4]) * isg[4]; t1 = (u1 - mu[5]) * isg[5];
    g.z = __expf(-0.5f * (t0 * t0 + t1 * t1));
    g.w = 0.f;
    return g;
}

// all 4 layers' 64x64 gauss tables
__global__ __launch_bounds__(256) void k_tables(const float* __restrict__ mu,
                                                const float* __restrict__ isg,
                                                const float* __restrict__ ppw,
                                                const float* __restrict__ ppb,
                                                float4* __restrict__ tbl) {
    int i = blockIdx.x * 256 + threadIdx.x;  // 4*4096
    int l = i >> 12;
    int idx = i & 4095;
    tbl[i] = gauss_direct(idx >> 6, idx & 63, mu + l * 6, isg + l * 6,
                          ppw + l * 4, ppb + l * 2);
}

// ---------------- weight transpose: wt4[l][q*12+m][cp] = {w(q*48+4m+i, cp)} ----------------
__global__ __launch_bounds__(256) void k_wprep(const float* __restrict__ fcw,
                                               float4* __restrict__ wt4) {
    int i = blockIdx.x * 256 + threadIdx.x;   // 4 * 3072 = 12288
    if (i >= 4 * 48 * 64) return;
    int l = i / 3072;         // layer
    int r = i - l * 3072;     // qm*64 + cp
    int qm = r >> 6;          // q*12+m  (0..47)
    int cp = r & 63;
    int j0 = qm * 4;          // k-index base
    const float* base = fcw + (size_t)l * KOUT * HID;
    float4 v;
    v.x = base[((j0 + 0) >> 6) * 4096 + cp * 64 + ((j0 + 0) & 63)];
    v.y = base[((j0 + 1) >> 6) * 4096 + cp * 64 + ((j0 + 1) & 63)];
    v.z = base[((j0 + 2) >> 6) * 4096 + cp * 64 + ((j0 + 2) & 63)];
    v.w = base[((j0 + 3) >> 6) * 4096 + cp * 64 + ((j0 + 3) & 63)];
    wt4[i] = v;
}

// ---------------- pull aggregation: one wave per node; a3 stored bf16 ----------------
// L0: exact f32 emb gather. Layers 1-3: bf16 mirror h2 (half the gather bytes).
template <bool L0>
__global__ __launch_bounds__(256) void k_pull(const int* __restrict__ rowptr,
                                              const unsigned* __restrict__ csr_e,
                                              const float4* __restrict__ tbl,
                                              const unsigned short* __restrict__ h2,
                                              const int* __restrict__ h_idx,
                                              const float* __restrict__ emb,
                                              const int* __restrict__ deg,
                                              const float* __restrict__ mu,
                                              const float* __restrict__ isg,
                                              const float* __restrict__ ppw,
                                              const float* __restrict__ ppb,
                                              unsigned short* __restrict__ a3h) {
    int n = blockIdx.x * 4 + (threadIdx.x >> 6);
    n = __builtin_amdgcn_readfirstlane(n);
    if (n >= N_NODES) return;
    int lane = threadIdx.x & 63;
    int beg = rowptr[n];
    int end = rowptr[n + 1];
    int dd = end - beg;
    float a0 = 0.f, a1 = 0.f, a2 = 0.f;

    auto getg = [&](unsigned r) -> float4 {
        unsigned gi = r >> 16;
        if (__builtin_expect(gi != 0xFFFFu, 1)) return tbl[gi];
        return gauss_direct(deg[r & 0xFFFFu], dd, mu, isg, ppw, ppb);
    };
    auto geth = [&](unsigned r) -> float {
        int s = (int)(r & 0xFFFFu);
        if (L0) return emb[h_idx[s] * HID + lane];
        return __uint_as_float((unsigned)h2[(size_t)s * HID + lane] << 16);
    };

    int p = beg;
    for (; p + 8 <= end; p += 8) {
        unsigned r[8];
#pragma unroll
        for (int u = 0; u < 8; ++u) r[u] = csr_e[p + u];
        float hv[8];
#pragma unroll
        for (int u = 0; u < 8; ++u) hv[u] = geth(r[u]);
#pragma unroll
        for (int u = 0; u < 8; ++u) {
            float4 g = getg(r[u]);
            a0 = fmaf(g.x, hv[u], a0); a1 = fmaf(g.y, hv[u], a1); a2 = fmaf(g.z, hv[u], a2);
        }
    }
    for (; p + 4 <= end; p += 4) {
        unsigned r0 = csr_e[p], r1 = csr_e[p + 1], r2 = csr_e[p + 2], r3 = csr_e[p + 3];
        float h0 = geth(r0), h1 = geth(r1), h2v = geth(r2), h3 = geth(r3);
        float4 g0 = getg(r0), g1 = getg(r1), g2 = getg(r2), g3 = getg(r3);
        a0 = fmaf(g0.x, h0, a0); a1 = fmaf(g0.y, h0, a1); a2 = fmaf(g0.z, h0, a2);
        a0 = fmaf(g1.x, h1, a0); a1 = fmaf(g1.y, h1, a1); a2 = fmaf(g1.z, h1, a2);
        a0 = fmaf(g2.x, h2v, a0); a1 = fmaf(g2.y, h2v, a1); a2 = fmaf(g2.z, h2v, a2);
        a0 = fmaf(g3.x, h3, a0); a1 = fmaf(g3.y, h3, a1); a2 = fmaf(g3.z, h3, a2);
    }
    for (; p < end; ++p) {
        unsigned r0 = csr_e[p];
        float h0 = geth(r0);
        float4 g0 = getg(r0);
        a0 = fmaf(g0.x, h0, a0); a1 = fmaf(g0.y, h0, a1); a2 = fmaf(g0.z, h0, a2);
    }
    unsigned short* out = a3h + (size_t)n * KOUT + lane;
    out[0] = f2bf(a0);
    out[64] = f2bf(a1);
    out[128] = f2bf(a2);
}

// ---------------- fc2: bf16 a3 in, weights (pre-transposed) coalesced, grid-stride ----------------
#define FC2_B 8
#define FC2_GRID 2048
__global__ __launch_bounds__(256) void k_fc2(const uint2* __restrict__ a3v,
                                             const float4* __restrict__ wt4,
                                             float* __restrict__ agg,
                                             float* __restrict__ bnpart) {
    __shared__ float4 sa4[FC2_B][49];   // 6.3 KB (f32, unpacked at stage time)
    __shared__ float sp[4][FC2_B][65];  // 8.3 KB
    __shared__ float bnp[4][128];       // 2 KB
    int t = threadIdx.x;
    int cp = t & 63;
    int q = t >> 6;
    float4 wv[12];
#pragma unroll
    for (int m = 0; m < 12; ++m) wv[m] = wt4[(q * 12 + m) * 64 + cp];
    float bnS = 0.f, bnQ = 0.f;
    for (int base = blockIdx.x * FC2_B; base < N_NODES; base += FC2_GRID * FC2_B) {
        __syncthreads();  // protect sa4/sp from previous batch
        // stage 8 nodes x 48 uint2 (4 bf16 each) = 384 -> unpack to float4
        for (int ii = t; ii < FC2_B * 48; ii += 256) {
            int nn = ii / 48, jj = ii - nn * 48;
            int node = base + nn;
            float4 v = make_float4(0.f, 0.f, 0.f, 0.f);
            if (node < N_NODES) {
                uint2 u = a3v[(size_t)node * 48 + jj];
                v.x = __uint_as_float(u.x << 16);
                v.y = __uint_as_float(u.x & 0xFFFF0000u);
                v.z = __uint_as_float(u.y << 16);
                v.w = __uint_as_float(u.y & 0xFFFF0000u);
            }
            sa4[nn][jj] = v;
        }
        __syncthreads();
        float acc[FC2_B];
#pragma unroll
        for (int nn = 0; nn < FC2_B; ++nn) acc[nn] = 0.f;
#pragma unroll
        for (int m = 0; m < 12; ++m) {
            float4 wm = wv[m];
#pragma unroll
            for (int nn = 0; nn < FC2_B; ++nn) {
                float4 s4 = sa4[nn][q * 12 + m];
                acc[nn] = fmaf(s4.x, wm.x, acc[nn]);
                acc[nn] = fmaf(s4.y, wm.y, acc[nn]);
                acc[nn] = fmaf(s4.z, wm.z, acc[nn]);
                acc[nn] = fmaf(s4.w, wm.w, acc[nn]);
            }
        }
#pragma unroll
        for (int nn = 0; nn < FC2_B; ++nn) sp[q][nn][cp] = acc[nn];
        __syncthreads();
#pragma unroll
        for (int i = 0; i < 2; ++i) {
            int nn = q + i * 4;
            int node = base + nn;
            if (node < N_NODES) {
                float v = sp[0][nn][cp] + sp[1][nn][cp] + sp[2][nn][cp] + sp[3][nn][cp];
                agg[(size_t)node * HID + cp] = v;
                bnS += v;
                bnQ += v * v;
            }
        }
    }
    __syncthreads();
    bnp[q][cp] = bnS;
    bnp[q][64 + cp] = bnQ;
    __syncthreads();
    if (t < 128) {
        float v = bnp[0][t] + bnp[1][t] + bnp[2][t] + bnp[3][t];
        bnpart[(size_t)t * FC2_GRID + blockIdx.x] = v;
    }
}

// ---------------- deterministic reduce of bnpart -> bnsum (128 blocks, coalesced) ----------------
__global__ __launch_bounds__(256) void k_bnred2(const float* __restrict__ bnpart,
                                                float* __restrict__ bnsum) {
    __shared__ float red[256];
    int c = blockIdx.x;   // channel 0..127
    int t = threadIdx.x;
    float acc = 0.f;
#pragma unroll
    for (int i = 0; i < FC2_GRID / 256; ++i)
        acc += bnpart[(size_t)c * FC2_GRID + i * 256 + t];
    red[t] = acc;
    __syncthreads();
    for (int off = 128; off > 0; off >>= 1) {
        if (t < off) red[t] += red[t + off];
        __syncthreads();
    }
    if (t == 0) bnsum[c] = red[0];
}

// ---------------- BN finalize + apply + residual (float4) -> h (f32) and h2 (bf16) ----------------
template <bool L0>
__global__ __launch_bounds__(256) void k_bnapply(const float4* __restrict__ agg4,
                                                 const float* __restrict__ bnsum,
                                                 const float* __restrict__ bng,
                                                 const float* __restrict__ bnb,
                                                 const int* __restrict__ h_idx,
                                                 const float4* __restrict__ emb4,
                                                 float4* __restrict__ h4,
                                                 unsigned short* __restrict__ h2) {
    __shared__ float ssc[128];
    int t = threadIdx.x;
    if (t < 64) {
        const float invN = 1.0f / (float)N_NODES;
        float mean = bnsum[t] * invN;
        float var = bnsum[64 + t] * invN - mean * mean;
        float scale = bng[t] * rsqrtf(var + EPS);
        ssc[t] = scale;
        ssc[64 + t] = bnb[t] - mean * scale;
    }
    __syncthreads();
    int i = blockIdx.x * 256 + t;  // over N_NODES*16 float4s
    if (i < N_NODES * 16) {
        int c4 = (i & 15) * 4;
        float4 ag = agg4[i];
        float4 hn;
        hn.x = fmaxf(fmaf(ag.x, ssc[c4 + 0], ssc[64 + c4 + 0]), 0.f);
        hn.y = fmaxf(fmaf(ag.y, ssc[c4 + 1], ssc[64 + c4 + 1]), 0.f);
        hn.z = fmaxf(fmaf(ag.z, ssc[c4 + 2], ssc[64 + c4 + 2]), 0.f);
        hn.w = fmaxf(fmaf(ag.w, ssc[c4 + 3], ssc[64 + c4 + 3]), 0.f);
        float4 base;
        if (L0) {
            int n = i >> 4;
            base = emb4[h_idx[n] * 16 + (i & 15)];
        } else {
            base = h4[i];
        }
        base.x += hn.x; base.y += hn.y; base.z += hn.z; base.w += hn.w;
        h4[i] = base;
        uint2 pk;
        pk.x = (unsigned)f2bf(base.x) | ((unsigned)f2bf(base.y) << 16);
        pk.y = (unsigned)f2bf(base.z) | ((unsigned)f2bf(base.w) << 16);
        *(uint2*)&h2[(size_t)i * 4] = pk;
    }
}

// ---------------- readout: wave per 64-node chunk, run-length accumulate ----------------
__global__ __launch_bounds__(256) void k_readout(const float* __restrict__ h,
                                                 const int* __restrict__ gid,
                                                 float* __restrict__ hg,
                                                 float* __restrict__ cnt) {
    int chunk = blockIdx.x * 4 + (threadIdx.x >> 6);
    int lane = threadIdx.x & 63;
    int n0 = chunk * 64;
    if (n0 >= N_NODES) return;
    int n1 = min(n0 + 64, N_NODES);
    int curg = gid[n0];
    float acc = 0.f;
    int count = 0;
    for (int n = n0; n < n1; ++n) {
        int g = gid[n];
        if (g != curg) {
            atomicAdd(&hg[(size_t)curg * HID + lane], acc);
            if (lane == 0) atomicAdd(&cnt[curg], (float)count);
            curg = g; acc = 0.f; count = 0;
        }
        acc += h[(size_t)n * HID + lane];
        ++count;
    }
    atomicAdd(&hg[(size_t)curg * HID + lane], acc);
    if (lane == 0) atomicAdd(&cnt[curg], (float)count);
}

// ---------------- MLP readout ----------------
__global__ __launch_bounds__(256) void k_mlp(const float* __restrict__ hg,
                                             const float* __restrict__ cnt,
                                             const float* __restrict__ w1, const float* __restrict__ b1,
                                             const float* __restrict__ w2, const float* __restrict__ b2,
                                             const float* __restrict__ w3, const float* __restrict__ b3,
                                             float* __restrict__ out) {
    int g = threadIdx.x;  // 256 threads, single block
    float inv = 1.0f / fmaxf(cnt[g], 1.0f);
    float x[HID];
#pragma unroll
    for (int i = 0; i < HID; ++i) x[i] = hg[(size_t)g * HID + i] * inv;
    float y1[32];
#pragma unroll
    for (int j = 0; j < 32; ++j) {
        float acc = b1[j];
#pragma unroll
        for (int i = 0; i < HID; ++i) acc = fmaf(x[i], w1[j * HID + i], acc);
        y1[j] = fmaxf(acc, 0.f);
    }
    float y2[16];
#pragma unroll
    for (int j = 0; j < 16; ++j) {
        float acc = b2[j];
#pragma unroll
        for (int i = 0; i < 32; ++i) acc = fmaf(y1[i], w2[j * 32 + i], acc);
        y2[j] = fmaxf(acc, 0.f);
    }
    float acc = b3[0];
#pragma unroll
    for (int i = 0; i < 16; ++i) acc = fmaf(y2[i], w3[i], acc);
    out[g] = acc;
}

extern "C" void kernel_launch(void* const* d_in, const int* in_sizes, int n_in,
                              void* d_out, int out_size, void* d_ws, size_t ws_size,
                              hipStream_t stream) {
    const int* h_idx = (const int*)d_in[0];
    const int* src = (const int*)d_in[1];
    const int* dst = (const int*)d_in[2];
    const int* gid = (const int*)d_in[3];
    const float* emb = (const float*)d_in[4];
    const float* fc_w = (const float*)d_in[5];
    const float* mu = (const float*)d_in[6];
    const float* isg = (const float*)d_in[7];
    const float* bng = (const float*)d_in[8];
    const float* bnb = (const float*)d_in[9];
    const float* ppw = (const float*)d_in[10];
    const float* ppb = (const float*)d_in[11];
    const float* w1 = (const float*)d_in[12];
    const float* b1 = (const float*)d_in[13];
    const float* w2 = (const float*)d_in[14];
    const float* b2 = (const float*)d_in[15];
    const float* w3 = (const float*)d_in[16];
    const float* b3 = (const float*)d_in[17];

    char* ws = (char*)d_ws;
    size_t o = 0;
    auto take = [&](size_t bytes) -> char* {
        char* p = ws + o;
        o += (bytes + 255) & ~(size_t)255;
        return p;
    };
    int* deg = (int*)take((size_t)N_NODES * 4);
    int* cursor = (int*)take((size_t)N_NODES * 4);
    int* rowptr = (int*)take((size_t)(N_NODES + 1) * 4);
    int* blocksum = (int*)take((size_t)NB1 * 4);
    int* blockoff = (int*)take((size_t)NB1 * 4);
    unsigned* csr_e = (unsigned*)take((size_t)N_EDGES * 4);
    float4* tbl = (float4*)take((size_t)4 * 4096 * 16);
    float4* wt4 = (float4*)take((size_t)4 * 48 * 64 * 16);  // 192 KB
    float* h = (float*)take((size_t)N_NODES * HID * 4);
    unsigned short* h2 = (unsigned short*)take((size_t)N_NODES * HID * 2);  // bf16 mirror
    unsigned short* a3h = (unsigned short*)take((size_t)N_NODES * KOUT * 2); // bf16 a3
    float* agg = (float*)take((size_t)N_NODES * HID * 4);
    float* bnpart = (float*)take((size_t)128 * FC2_GRID * 4);  // 1 MB channel-major
    float* bnsum = (float*)take(128 * 4);
    float* hg = (float*)take((size_t)N_GRAPHS * HID * 4);
    float* cnt = (float*)take((size_t)N_GRAPHS * 4);

    hipMemsetAsync(deg, 0, (size_t)N_NODES * 4, stream);
    hipMemsetAsync(hg, 0, (size_t)(N_GRAPHS * HID + N_GRAPHS) * 4, stream);

    k_deg<<<(N_EDGES + 255) / 256, 256, 0, stream>>>(dst, deg);
    k_scan1<<<NB1, 256, 0, stream>>>(deg, rowptr, blocksum);
    k_scan2<<<1, 256, 0, stream>>>(blocksum, blockoff);
    k_scan3<<<NB1, 256, 0, stream>>>(rowptr, blockoff, cursor);
    k_scatter<<<(N_EDGES + 255) / 256, 256, 0, stream>>>(src, dst, deg, cursor, csr_e);
    k_tables<<<(4 * 4096) / 256, 256, 0, stream>>>(mu, isg, ppw, ppb, tbl);
    k_wprep<<<(4 * 48 * 64 + 255) / 256, 256, 0, stream>>>(fc_w, wt4);

    for (int l = 0; l < 4; ++l) {
        const float* mul = mu + l * 6;
        const float* isgl = isg + l * 6;
        const float* ppwl = ppw + l * 4;
        const float* ppbl = ppb + l * 2;
        const float4* tbll = tbl + (size_t)l * 4096;
        if (l == 0)
            k_pull<true><<<(N_NODES + 3) / 4, 256, 0, stream>>>(rowptr, csr_e, tbll, h2,
                h_idx, emb, deg, mul, isgl, ppwl, ppbl, a3h);
        else
            k_pull<false><<<(N_NODES + 3) / 4, 256, 0, stream>>>(rowptr, csr_e, tbll, h2,
                h_idx, emb, deg, mul, isgl, ppwl, ppbl, a3h);
        k_fc2<<<FC2_GRID, 256, 0, stream>>>(
            (const uint2*)a3h, wt4 + (size_t)l * 48 * 64, agg, bnpart);
        k_bnred2<<<128, 256, 0, stream>>>(bnpart, bnsum);
        if (l == 0)
            k_bnapply<true><<<(N_NODES * 16 + 255) / 256, 256, 0, stream>>>(
                (const float4*)agg, bnsum, bng + l * 64, bnb + l * 64,
                h_idx, (const float4*)emb, (float4*)h, h2);
        else
            k_bnapply<false><<<(N_NODES * 16 + 255) / 256, 256, 0, stream>>>(
                (const float4*)agg, bnsum, bng + l * 64, bnb + l * 64,
                h_idx, (const float4*)emb, (float4*)h, h2);
    }

    k_readout<<<(N_NODES / 64 + 3) / 4 + 1, 256, 0, stream>>>(h, gid, hg, cnt);
    k_mlp<<<1, 256, 0, stream>>>(hg, cnt, w1, b1, w2, b2, w3, b3, (float*)d_out);
}

// Round 21
// 410.078 us; speedup vs baseline: 1.2730x; 1.0035x over previous
//
#include <hip/hip_runtime.h>
#include <hip/hip_bf16.h>

#define N_NODES 50000
#define N_EDGES 800000
#define N_GRAPHS 256
#define HID 64
#define KOUT 192   // K * OUT
#define EPS 1e-5f
#define NB1 196    // ceil(N_NODES / 256)

__device__ __forceinline__ unsigned short f2bf(float x) {
    unsigned u = __float_as_uint(x);
    unsigned r = (u + 0x7FFFu + ((u >> 16) & 1u)) >> 16;  // round-nearest-even
    return (unsigned short)r;
}

// ---------------- degree ----------------
__global__ void k_deg(const int* __restrict__ dst, int* __restrict__ deg) {
    int i = blockIdx.x * blockDim.x + threadIdx.x;
    if (i < N_EDGES) atomicAdd(&deg[dst[i]], 1);
}

// ---------------- hierarchical exclusive scan of deg -> rowptr ----------------
__global__ __launch_bounds__(256) void k_scan1(const int* __restrict__ deg,
                                               int* __restrict__ rowptr,
                                               int* __restrict__ blocksum) {
    __shared__ int sc[256];
    int t = threadIdx.x;
    int i = blockIdx.x * 256 + t;
    int v = (i < N_NODES) ? deg[i] : 0;
    sc[t] = v;
    __syncthreads();
    for (int off = 1; off < 256; off <<= 1) {
        int u = (t >= off) ? sc[t - off] : 0;
        __syncthreads();
        sc[t] += u;
        __syncthreads();
    }
    if (i < N_NODES) rowptr[i] = sc[t] - v;  // exclusive local prefix
    if (t == 255) blocksum[blockIdx.x] = sc[255];
}

__global__ __launch_bounds__(256) void k_scan2(const int* __restrict__ blocksum,
                                               int* __restrict__ blockoff) {
    __shared__ int sc[256];
    int t = threadIdx.x;
    int v = (t < NB1) ? blocksum[t] : 0;
    sc[t] = v;
    __syncthreads();
    for (int off = 1; off < 256; off <<= 1) {
        int u = (t >= off) ? sc[t - off] : 0;
        __syncthreads();
        sc[t] += u;
        __syncthreads();
    }
    if (t < NB1) blockoff[t] = sc[t] - v;
}

// rowptr[i] += blockoff[i>>8]; cursor[i] = rowptr[i]; rowptr[N]=E
__global__ __launch_bounds__(256) void k_scan3(int* __restrict__ rowptr,
                                               const int* __restrict__ blockoff,
                                               int* __restrict__ cursor) {
    int i = blockIdx.x * 256 + threadIdx.x;
    if (i < N_NODES) {
        int r = rowptr[i] + blockoff[i >> 8];
        rowptr[i] = r;
        cursor[i] = r;
    }
    if (i == 0) rowptr[N_NODES] = N_EDGES;
}

// ---------------- XCD-localized scatter: 8 dst-ranges, blockIdx&7 selects range ----------------
// Range r owns nodes [r*6250, r*6250+6250); its csr span (~400 KB) stays in one XCD's L2.
#define SC_RANGES 8
#define SC_NPR (N_NODES / SC_RANGES)   // 6250
#define SC_CHUNK 3200
#define SC_NCHUNK ((N_EDGES + SC_CHUNK - 1) / SC_CHUNK)  // 250
__global__ __launch_bounds__(256) void k_scatter(const int* __restrict__ src,
                                                 const int* __restrict__ dst,
                                                 const int* __restrict__ deg,
                                                 int* __restrict__ cursor,
                                                 unsigned* __restrict__ csr_e) {
    int r = blockIdx.x & (SC_RANGES - 1);
    int chunk = blockIdx.x >> 3;
    int lo = r * SC_NPR;
    int hi = lo + SC_NPR;
    int base = chunk * SC_CHUNK;
    int end = min(base + SC_CHUNK, N_EDGES);
    for (int e = base + threadIdx.x; e < end; e += 256) {
        int d = dst[e];
        if (d >= lo && d < hi) {
            int s = src[e];
            int p = atomicAdd(&cursor[d], 1);
            int ds = deg[s], dd = deg[d];
            unsigned gi = (ds < 64 && dd < 64) ? (unsigned)(ds * 64 + dd) : 0xFFFFu;
            csr_e[p] = (unsigned)s | (gi << 16);
        }
    }
}

// ---------------- gaussian from degrees (shared by table + fallback) ----------------
__device__ __forceinline__ float4 gauss_direct(int degs, int degd,
                                               const float* __restrict__ mu,
                                               const float* __restrict__ isg,
                                               const float* __restrict__ ppw,
                                               const float* __restrict__ ppb) {
    float p0 = rsqrtf((float)degs + 1.0f);
    float p1 = rsqrtf((float)degd + 1.0f);
    float u0 = tanhf(fmaf(p1, ppw[1], fmaf(p0, ppw[0], ppb[0])));
    float u1 = tanhf(fmaf(p1, ppw[3], fmaf(p0, ppw[2], ppb[1])));
    float4 g;
    float t0, t1;
    t0 = (u0 - mu[0]) * isg[0]; t1 = (u1 - mu[1]) * isg[1];
    g.x = __expf(-0.5f * (t0 * t0 + t1 * t1));
    t0 = (u0 - mu[2]) * isg[2]; t1 = (u1 - mu[3]) * isg[3];
    g.y = __expf(-0.5f * (t0 * t0 + t1 * t1));
    t0 = (u0 - mu[4]) * isg[4]; t1 = (u1 - mu[5]) * isg[5];
    g.z = __expf(-0.5f * (t0 * t0 + t1 * t1));
    g.w = 0.f;
    return g;
}

// all 4 layers' 64x64 gauss tables
__global__ __launch_bounds__(256) void k_tables(const float* __restrict__ mu,
                                                const float* __restrict__ isg,
                                                const float* __restrict__ ppw,
                                                const float* __restrict__ ppb,
                                                float4* __restrict__ tbl) {
    int i = blockIdx.x * 256 + threadIdx.x;  // 4*4096
    int l = i >> 12;
    int idx = i & 4095;
    tbl[i] = gauss_direct(idx >> 6, idx & 63, mu + l * 6, isg + l * 6,
                          ppw + l * 4, ppb + l * 2);
}

// ---------------- weight transpose: wt4[l][q*12+m][cp] = {w(q*48+4m+i, cp)} ----------------
__global__ __launch_bounds__(256) void k_wprep(const float* __restrict__ fcw,
                                               float4* __restrict__ wt4) {
    int i = blockIdx.x * 256 + threadIdx.x;   // 4 * 3072 = 12288
    if (i >= 4 * 48 * 64) return;
    int l = i / 3072;         // layer
    int r = i - l * 3072;     // qm*64 + cp
    int qm = r >> 6;          // q*12+m  (0..47)
    int cp = r & 63;
    int j0 = qm * 4;          // k-index base
    const float* base = fcw + (size_t)l * KOUT * HID;
    float4 v;
    v.x = base[((j0 + 0) >> 6) * 4096 + cp * 64 + ((j0 + 0) & 63)];
    v.y = base[((j0 + 1) >> 6) * 4096 + cp * 64 + ((j0 + 1) & 63)];
    v.z = base[((j0 + 2) >> 6) * 4096 + cp * 64 + ((j0 + 2) & 63)];
    v.w = base[((j0 + 3) >> 6) * 4096 + cp * 64 + ((j0 + 3) & 63)];
    wt4[i] = v;
}

// ---------------- pull aggregation: one wave per node; a3 stored bf16 ----------------
// L0: exact f32 emb gather. Layers 1-3: bf16 mirror h2 (half the gather bytes).
template <bool L0>
__global__ __launch_bounds__(256) void k_pull(const int* __restrict__ rowptr,
                                              const unsigned* __restrict__ csr_e,
                                              const float4* __restrict__ tbl,
                                              const unsigned short* __restrict__ h2,
                                              const int* __restrict__ h_idx,
                                              const float* __restrict__ emb,
                                              const int* __restrict__ deg,
                                              const float* __restrict__ mu,
                                              const float* __restrict__ isg,
                                              const float* __restrict__ ppw,
                                              const float* __restrict__ ppb,
                                              unsigned short* __restrict__ a3h) {
    int n = blockIdx.x * 4 + (threadIdx.x >> 6);
    n = __builtin_amdgcn_readfirstlane(n);
    if (n >= N_NODES) return;
    int lane = threadIdx.x & 63;
    int beg = rowptr[n];
    int end = rowptr[n + 1];
    int dd = end - beg;
    float a0 = 0.f, a1 = 0.f, a2 = 0.f;

    auto getg = [&](unsigned r) -> float4 {
        unsigned gi = r >> 16;
        if (__builtin_expect(gi != 0xFFFFu, 1)) return tbl[gi];
        return gauss_direct(deg[r & 0xFFFFu], dd, mu, isg, ppw, ppb);
    };
    auto geth = [&](unsigned r) -> float {
        int s = (int)(r & 0xFFFFu);
        if (L0) return emb[h_idx[s] * HID + lane];
        return __uint_as_float((unsigned)h2[(size_t)s * HID + lane] << 16);
    };

    int p = beg;
    for (; p + 8 <= end; p += 8) {
        unsigned r[8];
#pragma unroll
        for (int u = 0; u < 8; ++u) r[u] = csr_e[p + u];
        float hv[8];
#pragma unroll
        for (int u = 0; u < 8; ++u) hv[u] = geth(r[u]);
#pragma unroll
        for (int u = 0; u < 8; ++u) {
            float4 g = getg(r[u]);
            a0 = fmaf(g.x, hv[u], a0); a1 = fmaf(g.y, hv[u], a1); a2 = fmaf(g.z, hv[u], a2);
        }
    }
    for (; p + 4 <= end; p += 4) {
        unsigned r0 = csr_e[p], r1 = csr_e[p + 1], r2 = csr_e[p + 2], r3 = csr_e[p + 3];
        float h0 = geth(r0), h1 = geth(r1), h2v = geth(r2), h3 = geth(r3);
        float4 g0 = getg(r0), g1 = getg(r1), g2 = getg(r2), g3 = getg(r3);
        a0 = fmaf(g0.x, h0, a0); a1 = fmaf(g0.y, h0, a1); a2 = fmaf(g0.z, h0, a2);
        a0 = fmaf(g1.x, h1, a0); a1 = fmaf(g1.y, h1, a1); a2 = fmaf(g1.z, h1, a2);
        a0 = fmaf(g2.x, h2v, a0); a1 = fmaf(g2.y, h2v, a1); a2 = fmaf(g2.z, h2v, a2);
        a0 = fmaf(g3.x, h3, a0); a1 = fmaf(g3.y, h3, a1); a2 = fmaf(g3.z, h3, a2);
    }
    for (; p < end; ++p) {
        unsigned r0 = csr_e[p];
        float h0 = geth(r0);
        float4 g0 = getg(r0);
        a0 = fmaf(g0.x, h0, a0); a1 = fmaf(g0.y, h0, a1); a2 = fmaf(g0.z, h0, a2);
    }
    unsigned short* out = a3h + (size_t)n * KOUT + lane;
    out[0] = f2bf(a0);
    out[64] = f2bf(a1);
    out[128] = f2bf(a2);
}

// ---------------- fc2: bf16 a3 in, weights (pre-transposed) coalesced, grid-stride ----------------
#define FC2_B 8
#define FC2_GRID 2048
__global__ __launch_bounds__(256) void k_fc2(const uint2* __restrict__ a3v,
                                             const float4* __restrict__ wt4,
                                             float* __restrict__ agg,
                                             float* __restrict__ bnpart) {
    __shared__ float4 sa4[FC2_B][49];   // 6.3 KB (f32, unpacked at stage time)
    __shared__ float sp[4][FC2_B][65];  // 8.3 KB
    __shared__ float bnp[4][128];       // 2 KB
    int t = threadIdx.x;
    int cp = t & 63;
    int q = t >> 6;
    float4 wv[12];
#pragma unroll
    for (int m = 0; m < 12; ++m) wv[m] = wt4[(q * 12 + m) * 64 + cp];
    float bnS = 0.f, bnQ = 0.f;
    for (int base = blockIdx.x * FC2_B; base < N_NODES; base += FC2_GRID * FC2_B) {
        __syncthreads();  // protect sa4/sp from previous batch
        // stage 8 nodes x 48 uint2 (4 bf16 each) = 384 -> unpack to float4
        for (int ii = t; ii < FC2_B * 48; ii += 256) {
            int nn = ii / 48, jj = ii - nn * 48;
            int node = base + nn;
            float4 v = make_float4(0.f, 0.f, 0.f, 0.f);
            if (node < N_NODES) {
                uint2 u = a3v[(size_t)node * 48 + jj];
                v.x = __uint_as_float(u.x << 16);
                v.y = __uint_as_float(u.x & 0xFFFF0000u);
                v.z = __uint_as_float(u.y << 16);
                v.w = __uint_as_float(u.y & 0xFFFF0000u);
            }
            sa4[nn][jj] = v;
        }
        __syncthreads();
        float acc[FC2_B];
#pragma unroll
        for (int nn = 0; nn < FC2_B; ++nn) acc[nn] = 0.f;
#pragma unroll
        for (int m = 0; m < 12; ++m) {
            float4 wm = wv[m];
#pragma unroll
            for (int nn = 0; nn < FC2_B; ++nn) {
                float4 s4 = sa4[nn][q * 12 + m];
                acc[nn] = fmaf(s4.x, wm.x, acc[nn]);
                acc[nn] = fmaf(s4.y, wm.y, acc[nn]);
                acc[nn] = fmaf(s4.z, wm.z, acc[nn]);
                acc[nn] = fmaf(s4.w, wm.w, acc[nn]);
            }
        }
#pragma unroll
        for (int nn = 0; nn < FC2_B; ++nn) sp[q][nn][cp] = acc[nn];
        __syncthreads();
#pragma unroll
        for (int i = 0; i < 2; ++i) {
            int nn = q + i * 4;
            int node = base + nn;
            if (node < N_NODES) {
                float v = sp[0][nn][cp] + sp[1][nn][cp] + sp[2][nn][cp] + sp[3][nn][cp];
                agg[(size_t)node * HID + cp] = v;
                bnS += v;
                bnQ += v * v;
            }
        }
    }
    __syncthreads();
    bnp[q][cp] = bnS;
    bnp[q][64 + cp] = bnQ;
    __syncthreads();
    if (t < 128) {
        float v = bnp[0][t] + bnp[1][t] + bnp[2][t] + bnp[3][t];
        bnpart[(size_t)t * FC2_GRID + blockIdx.x] = v;
    }
}

// ---------------- deterministic reduce of bnpart -> bnsum (128 blocks, coalesced) ----------------
__global__ __launch_bounds__(256) void k_bnred2(const float* __restrict__ bnpart,
                                                float* __restrict__ bnsum) {
    __shared__ float red[256];
    int c = blockIdx.x;   // channel 0..127
    int t = threadIdx.x;
    float acc = 0.f;
#pragma unroll
    for (int i = 0; i < FC2_GRID / 256; ++i)
        acc += bnpart[(size_t)c * FC2_GRID + i * 256 + t];
    red[t] = acc;
    __syncthreads();
    for (int off = 128; off > 0; off >>= 1) {
        if (t < off) red[t] += red[t + off];
        __syncthreads();
    }
    if (t == 0) bnsum[c] = red[0];
}

// ---------------- BN finalize + apply + residual (float4) -> h (f32) and h2 (bf16) ----------------
template <bool L0>
__global__ __launch_bounds__(256) void k_bnapply(const float4* __restrict__ agg4,
                                                 const float* __restrict__ bnsum,
                                                 const float* __restrict__ bng,
                                                 const float* __restrict__ bnb,
                                                 const int* __restrict__ h_idx,
                                                 const float4* __restrict__ emb4,
                                                 float4* __restrict__ h4,
                                                 unsigned short* __restrict__ h2) {
    __shared__ float ssc[128];
    int t = threadIdx.x;
    if (t < 64) {
        const float invN = 1.0f / (float)N_NODES;
        float mean = bnsum[t] * invN;
        float var = bnsum[64 + t] * invN - mean * mean;
        float scale = bng[t] * rsqrtf(var + EPS);
        ssc[t] = scale;
        ssc[64 + t] = bnb[t] - mean * scale;
    }
    __syncthreads();
    int i = blockIdx.x * 256 + t;  // over N_NODES*16 float4s
    if (i < N_NODES * 16) {
        int c4 = (i & 15) * 4;
        float4 ag = agg4[i];
        float4 hn;
        hn.x = fmaxf(fmaf(ag.x, ssc[c4 + 0], ssc[64 + c4 + 0]), 0.f);
        hn.y = fmaxf(fmaf(ag.y, ssc[c4 + 1], ssc[64 + c4 + 1]), 0.f);
        hn.z = fmaxf(fmaf(ag.z, ssc[c4 + 2], ssc[64 + c4 + 2]), 0.f);
        hn.w = fmaxf(fmaf(ag.w, ssc[c4 + 3], ssc[64 + c4 + 3]), 0.f);
        float4 base;
        if (L0) {
            int n = i >> 4;
            base = emb4[h_idx[n] * 16 + (i & 15)];
        } else {
            base = h4[i];
        }
        base.x += hn.x; base.y += hn.y; base.z += hn.z; base.w += hn.w;
        h4[i] = base;
        uint2 pk;
        pk.x = (unsigned)f2bf(base.x) | ((unsigned)f2bf(base.y) << 16);
        pk.y = (unsigned)f2bf(base.z) | ((unsigned)f2bf(base.w) << 16);
        *(uint2*)&h2[(size_t)i * 4] = pk;
    }
}

// ---------------- readout: wave per 64-node chunk, run-length accumulate ----------------
__global__ __launch_bounds__(256) void k_readout(const float* __restrict__ h,
                                                 const int* __restrict__ gid,
                                                 float* __restrict__ hg,
                                                 float* __restrict__ cnt) {
    int chunk = blockIdx.x * 4 + (threadIdx.x >> 6);
    int lane = threadIdx.x & 63;
    int n0 = chunk * 64;
    if (n0 >= N_NODES) return;
    int n1 = min(n0 + 64, N_NODES);
    int curg = gid[n0];
    float acc = 0.f;
    int count = 0;
    for (int n = n0; n < n1; ++n) {
        int g = gid[n];
        if (g != curg) {
            atomicAdd(&hg[(size_t)curg * HID + lane], acc);
            if (lane == 0) atomicAdd(&cnt[curg], (float)count);
            curg = g; acc = 0.f; count = 0;
        }
        acc += h[(size_t)n * HID + lane];
        ++count;
    }
    atomicAdd(&hg[(size_t)curg * HID + lane], acc);
    if (lane == 0) atomicAdd(&cnt[curg], (float)count);
}

// ---------------- MLP readout ----------------
__global__ __launch_bounds__(256) void k_mlp(const float* __restrict__ hg,
                                             const float* __restrict__ cnt,
                                             const float* __restrict__ w1, const float* __restrict__ b1,
                                             const float* __restrict__ w2, const float* __restrict__ b2,
                                             const float* __restrict__ w3, const float* __restrict__ b3,
                                             float* __restrict__ out) {
    int g = threadIdx.x;  // 256 threads, single block
    float inv = 1.0f / fmaxf(cnt[g], 1.0f);
    float x[HID];
#pragma unroll
    for (int i = 0; i < HID; ++i) x[i] = hg[(size_t)g * HID + i] * inv;
    float y1[32];
#pragma unroll
    for (int j = 0; j < 32; ++j) {
        float acc = b1[j];
#pragma unroll
        for (int i = 0; i < HID; ++i) acc = fmaf(x[i], w1[j * HID + i], acc);
        y1[j] = fmaxf(acc, 0.f);
    }
    float y2[16];
#pragma unroll
    for (int j = 0; j < 16; ++j) {
        float acc = b2[j];
#pragma unroll
        for (int i = 0; i < 32; ++i) acc = fmaf(y1[i], w2[j * 32 + i], acc);
        y2[j] = fmaxf(acc, 0.f);
    }
    float acc = b3[0];
#pragma unroll
    for (int i = 0; i < 16; ++i) acc = fmaf(y2[i], w3[i], acc);
    out[g] = acc;
}

extern "C" void kernel_launch(void* const* d_in, const int* in_sizes, int n_in,
                              void* d_out, int out_size, void* d_ws, size_t ws_size,
                              hipStream_t stream) {
    const int* h_idx = (const int*)d_in[0];
    const int* src = (const int*)d_in[1];
    const int* dst = (const int*)d_in[2];
    const int* gid = (const int*)d_in[3];
    const float* emb = (const float*)d_in[4];
    const float* fc_w = (const float*)d_in[5];
    const float* mu = (const float*)d_in[6];
    const float* isg = (const float*)d_in[7];
    const float* bng = (const float*)d_in[8];
    const float* bnb = (const float*)d_in[9];
    const float* ppw = (const float*)d_in[10];
    const float* ppb = (const float*)d_in[11];
    const float* w1 = (const float*)d_in[12];
    const float* b1 = (const float*)d_in[13];
    const float* w2 = (const float*)d_in[14];
    const float* b2 = (const float*)d_in[15];
    const float* w3 = (const float*)d_in[16];
    const float* b3 = (const float*)d_in[17];

    char* ws = (char*)d_ws;
    size_t o = 0;
    auto take = [&](size_t bytes) -> char* {
        char* p = ws + o;
        o += (bytes + 255) & ~(size_t)255;
        return p;
    };
    int* deg = (int*)take((size_t)N_NODES * 4);
    int* cursor = (int*)take((size_t)N_NODES * 4);
    int* rowptr = (int*)take((size_t)(N_NODES + 1) * 4);
    int* blocksum = (int*)take((size_t)NB1 * 4);
    int* blockoff = (int*)take((size_t)NB1 * 4);
    unsigned* csr_e = (unsigned*)take((size_t)N_EDGES * 4);
    float4* tbl = (float4*)take((size_t)4 * 4096 * 16);
    float4* wt4 = (float4*)take((size_t)4 * 48 * 64 * 16);  // 192 KB
    float* h = (float*)take((size_t)N_NODES * HID * 4);
    unsigned short* h2 = (unsigned short*)take((size_t)N_NODES * HID * 2);  // bf16 mirror
    unsigned short* a3h = (unsigned short*)take((size_t)N_NODES * KOUT * 2); // bf16 a3
    float* agg = (float*)take((size_t)N_NODES * HID * 4);
    float* bnpart = (float*)take((size_t)128 * FC2_GRID * 4);  // 1 MB channel-major
    float* bnsum = (float*)take(128 * 4);
    float* hg = (float*)take((size_t)N_GRAPHS * HID * 4);
    float* cnt = (float*)take((size_t)N_GRAPHS * 4);

    hipMemsetAsync(deg, 0, (size_t)N_NODES * 4, stream);
    hipMemsetAsync(hg, 0, (size_t)(N_GRAPHS * HID + N_GRAPHS) * 4, stream);

    k_deg<<<(N_EDGES + 255) / 256, 256, 0, stream>>>(dst, deg);
    k_scan1<<<NB1, 256, 0, stream>>>(deg, rowptr, blocksum);
    k_scan2<<<1, 256, 0, stream>>>(blocksum, blockoff);
    k_scan3<<<NB1, 256, 0, stream>>>(rowptr, blockoff, cursor);
    k_scatter<<<SC_RANGES * SC_NCHUNK, 256, 0, stream>>>(src, dst, deg, cursor, csr_e);
    k_tables<<<(4 * 4096) / 256, 256, 0, stream>>>(mu, isg, ppw, ppb, tbl);
    k_wprep<<<(4 * 48 * 64 + 255) / 256, 256, 0, stream>>>(fc_w, wt4);

    for (int l = 0; l < 4; ++l) {
        const float* mul = mu + l * 6;
        const float* isgl = isg + l * 6;
        const float* ppwl = ppw + l * 4;
        const float* ppbl = ppb + l * 2;
        const float4* tbll = tbl + (size_t)l * 4096;
        if (l == 0)
            k_pull<true><<<(N_NODES + 3) / 4, 256, 0, stream>>>(rowptr, csr_e, tbll, h2,
                h_idx, emb, deg, mul, isgl, ppwl, ppbl, a3h);
        else
            k_pull<false><<<(N_NODES + 3) / 4, 256, 0, stream>>>(rowptr, csr_e, tbll, h2,
                h_idx, emb, deg, mul, isgl, ppwl, ppbl, a3h);
        k_fc2<<<FC2_GRID, 256, 0, stream>>>(
            (const uint2*)a3h, wt4 + (size_t)l * 48 * 64, agg, bnpart);
        k_bnred2<<<128, 256, 0, stream>>>(bnpart, bnsum);
        if (l == 0)
            k_bnapply<true><<<(N_NODES * 16 + 255) / 256, 256, 0, stream>>>(
                (const float4*)agg, bnsum, bng + l * 64, bnb + l * 64,
                h_idx, (const float4*)emb, (float4*)h, h2);
        else
            k_bnapply<false><<<(N_NODES * 16 + 255) / 256, 256, 0, stream>>>(
                (const float4*)agg, bnsum, bng + l * 64, bnb + l * 64,
                h_idx, (const float4*)emb, (float4*)h, h2);
    }

    k_readout<<<(N_NODES / 64 + 3) / 4 + 1, 256, 0, stream>>>(h, gid, hg, cnt);
    k_mlp<<<1, 256, 0, stream>>>(hg, cnt, w1, b1, w2, b2, w3, b3, (float*)d_out);
}

// Round 22
// 389.233 us; speedup vs baseline: 1.3411x; 1.0536x over previous
//
#include <hip/hip_runtime.h>
#include <hip/hip_bf16.h>

#define N_NODES 50000
#define N_EDGES 800000
#define N_GRAPHS 256
#define HID 64
#define KOUT 192   // K * OUT
#define EPS 1e-5f
#define NB1 196    // ceil(N_NODES / 256)

__device__ __forceinline__ unsigned short f2bf(float x) {
    unsigned u = __float_as_uint(x);
    unsigned r = (u + 0x7FFFu + ((u >> 16) & 1u)) >> 16;  // round-nearest-even
    return (unsigned short)r;
}

// ---------------- degree ----------------
__global__ void k_deg(const int* __restrict__ dst, int* __restrict__ deg) {
    int i = blockIdx.x * blockDim.x + threadIdx.x;
    if (i < N_EDGES) atomicAdd(&deg[dst[i]], 1);
}

// ---------------- hierarchical exclusive scan of deg -> rowptr ----------------
__global__ __launch_bounds__(256) void k_scan1(const int* __restrict__ deg,
                                               int* __restrict__ rowptr,
                                               int* __restrict__ blocksum) {
    __shared__ int sc[256];
    int t = threadIdx.x;
    int i = blockIdx.x * 256 + t;
    int v = (i < N_NODES) ? deg[i] : 0;
    sc[t] = v;
    __syncthreads();
    for (int off = 1; off < 256; off <<= 1) {
        int u = (t >= off) ? sc[t - off] : 0;
        __syncthreads();
        sc[t] += u;
        __syncthreads();
    }
    if (i < N_NODES) rowptr[i] = sc[t] - v;  // exclusive local prefix
    if (t == 255) blocksum[blockIdx.x] = sc[255];
}

__global__ __launch_bounds__(256) void k_scan2(const int* __restrict__ blocksum,
                                               int* __restrict__ blockoff) {
    __shared__ int sc[256];
    int t = threadIdx.x;
    int v = (t < NB1) ? blocksum[t] : 0;
    sc[t] = v;
    __syncthreads();
    for (int off = 1; off < 256; off <<= 1) {
        int u = (t >= off) ? sc[t - off] : 0;
        __syncthreads();
        sc[t] += u;
        __syncthreads();
    }
    if (t < NB1) blockoff[t] = sc[t] - v;
}

// rowptr[i] += blockoff[i>>8]; cursor[i] = rowptr[i]; rowptr[N]=E
__global__ __launch_bounds__(256) void k_scan3(int* __restrict__ rowptr,
                                               const int* __restrict__ blockoff,
                                               int* __restrict__ cursor) {
    int i = blockIdx.x * 256 + threadIdx.x;
    if (i < N_NODES) {
        int r = rowptr[i] + blockoff[i >> 8];
        rowptr[i] = r;
        cursor[i] = r;
    }
    if (i == 0) rowptr[N_NODES] = N_EDGES;
}

// ---------------- XCD-localized scatter: 8 dst-ranges, blockIdx&7 selects range ----------------
#define SC_RANGES 8
#define SC_NPR (N_NODES / SC_RANGES)   // 6250
#define SC_CHUNK 3200
#define SC_NCHUNK ((N_EDGES + SC_CHUNK - 1) / SC_CHUNK)  // 250
__global__ __launch_bounds__(256) void k_scatter(const int* __restrict__ src,
                                                 const int* __restrict__ dst,
                                                 const int* __restrict__ deg,
                                                 int* __restrict__ cursor,
                                                 unsigned* __restrict__ csr_e) {
    int r = blockIdx.x & (SC_RANGES - 1);
    int chunk = blockIdx.x >> 3;
    int lo = r * SC_NPR;
    int hi = lo + SC_NPR;
    int base = chunk * SC_CHUNK;
    int end = min(base + SC_CHUNK, N_EDGES);
    for (int e = base + threadIdx.x; e < end; e += 256) {
        int d = dst[e];
        if (d >= lo && d < hi) {
            int s = src[e];
            int p = atomicAdd(&cursor[d], 1);
            int ds = deg[s], dd = deg[d];
            unsigned gi = (ds < 64 && dd < 64) ? (unsigned)(ds * 64 + dd) : 0xFFFFu;
            csr_e[p] = (unsigned)s | (gi << 16);
        }
    }
}

// ---------------- gaussian from degrees (shared by table + fallback) ----------------
__device__ __forceinline__ float4 gauss_direct(int degs, int degd,
                                               const float* __restrict__ mu,
                                               const float* __restrict__ isg,
                                               const float* __restrict__ ppw,
                                               const float* __restrict__ ppb) {
    float p0 = rsqrtf((float)degs + 1.0f);
    float p1 = rsqrtf((float)degd + 1.0f);
    float u0 = tanhf(fmaf(p1, ppw[1], fmaf(p0, ppw[0], ppb[0])));
    float u1 = tanhf(fmaf(p1, ppw[3], fmaf(p0, ppw[2], ppb[1])));
    float4 g;
    float t0, t1;
    t0 = (u0 - mu[0]) * isg[0]; t1 = (u1 - mu[1]) * isg[1];
    g.x = __expf(-0.5f * (t0 * t0 + t1 * t1));
    t0 = (u0 - mu[2]) * isg[2]; t1 = (u1 - mu[3]) * isg[3];
    g.y = __expf(-0.5f * (t0 * t0 + t1 * t1));
    t0 = (u0 - mu[4]) * isg[4]; t1 = (u1 - mu[5]) * isg[5];
    g.z = __expf(-0.5f * (t0 * t0 + t1 * t1));
    g.w = 0.f;
    return g;
}

// all 4 layers' 64x64 gauss tables
__global__ __launch_bounds__(256) void k_tables(const float* __restrict__ mu,
                                                const float* __restrict__ isg,
                                                const float* __restrict__ ppw,
                                                const float* __restrict__ ppb,
                                                float4* __restrict__ tbl) {
    int i = blockIdx.x * 256 + threadIdx.x;  // 4*4096
    int l = i >> 12;
    int idx = i & 4095;
    tbl[i] = gauss_direct(idx >> 6, idx & 63, mu + l * 6, isg + l * 6,
                          ppw + l * 4, ppb + l * 2);
}

// ---------------- weight transpose: wt4[l][q*12+m][cp] = {w(q*48+4m+i, cp)} ----------------
__global__ __launch_bounds__(256) void k_wprep(const float* __restrict__ fcw,
                                               float4* __restrict__ wt4) {
    int i = blockIdx.x * 256 + threadIdx.x;   // 4 * 3072 = 12288
    if (i >= 4 * 48 * 64) return;
    int l = i / 3072;         // layer
    int r = i - l * 3072;     // qm*64 + cp
    int qm = r >> 6;          // q*12+m  (0..47)
    int cp = r & 63;
    int j0 = qm * 4;          // k-index base
    const float* base = fcw + (size_t)l * KOUT * HID;
    float4 v;
    v.x = base[((j0 + 0) >> 6) * 4096 + cp * 64 + ((j0 + 0) & 63)];
    v.y = base[((j0 + 1) >> 6) * 4096 + cp * 64 + ((j0 + 1) & 63)];
    v.z = base[((j0 + 2) >> 6) * 4096 + cp * 64 + ((j0 + 2) & 63)];
    v.w = base[((j0 + 3) >> 6) * 4096 + cp * 64 + ((j0 + 3) & 63)];
    wt4[i] = v;
}

// ---------------- pull aggregation: one wave per node; a3 stored bf16 ----------------
template <bool L0>
__global__ __launch_bounds__(256) void k_pull(const int* __restrict__ rowptr,
                                              const unsigned* __restrict__ csr_e,
                                              const float4* __restrict__ tbl,
                                              const unsigned short* __restrict__ h2,
                                              const int* __restrict__ h_idx,
                                              const float* __restrict__ emb,
                                              const int* __restrict__ deg,
                                              const float* __restrict__ mu,
                                              const float* __restrict__ isg,
                                              const float* __restrict__ ppw,
                                              const float* __restrict__ ppb,
                                              unsigned short* __restrict__ a3h) {
    int n = blockIdx.x * 4 + (threadIdx.x >> 6);
    n = __builtin_amdgcn_readfirstlane(n);
    if (n >= N_NODES) return;
    int lane = threadIdx.x & 63;
    int beg = rowptr[n];
    int end = rowptr[n + 1];
    int dd = end - beg;
    float a0 = 0.f, a1 = 0.f, a2 = 0.f;

    auto getg = [&](unsigned r) -> float4 {
        unsigned gi = r >> 16;
        if (__builtin_expect(gi != 0xFFFFu, 1)) return tbl[gi];
        return gauss_direct(deg[r & 0xFFFFu], dd, mu, isg, ppw, ppb);
    };
    auto geth = [&](unsigned r) -> float {
        int s = (int)(r & 0xFFFFu);
        if (L0) return emb[h_idx[s] * HID + lane];
        return __uint_as_float((unsigned)h2[(size_t)s * HID + lane] << 16);
    };

    int p = beg;
    for (; p + 8 <= end; p += 8) {
        unsigned r[8];
#pragma unroll
        for (int u = 0; u < 8; ++u) r[u] = csr_e[p + u];
        float hv[8];
#pragma unroll
        for (int u = 0; u < 8; ++u) hv[u] = geth(r[u]);
#pragma unroll
        for (int u = 0; u < 8; ++u) {
            float4 g = getg(r[u]);
            a0 = fmaf(g.x, hv[u], a0); a1 = fmaf(g.y, hv[u], a1); a2 = fmaf(g.z, hv[u], a2);
        }
    }
    for (; p + 4 <= end; p += 4) {
        unsigned r0 = csr_e[p], r1 = csr_e[p + 1], r2 = csr_e[p + 2], r3 = csr_e[p + 3];
        float h0 = geth(r0), h1 = geth(r1), h2v = geth(r2), h3 = geth(r3);
        float4 g0 = getg(r0), g1 = getg(r1), g2 = getg(r2), g3 = getg(r3);
        a0 = fmaf(g0.x, h0, a0); a1 = fmaf(g0.y, h0, a1); a2 = fmaf(g0.z, h0, a2);
        a0 = fmaf(g1.x, h1, a0); a1 = fmaf(g1.y, h1, a1); a2 = fmaf(g1.z, h1, a2);
        a0 = fmaf(g2.x, h2v, a0); a1 = fmaf(g2.y, h2v, a1); a2 = fmaf(g2.z, h2v, a2);
        a0 = fmaf(g3.x, h3, a0); a1 = fmaf(g3.y, h3, a1); a2 = fmaf(g3.z, h3, a2);
    }
    for (; p < end; ++p) {
        unsigned r0 = csr_e[p];
        float h0 = geth(r0);
        float4 g0 = getg(r0);
        a0 = fmaf(g0.x, h0, a0); a1 = fmaf(g0.y, h0, a1); a2 = fmaf(g0.z, h0, a2);
    }
    unsigned short* out = a3h + (size_t)n * KOUT + lane;
    out[0] = f2bf(a0);
    out[64] = f2bf(a1);
    out[128] = f2bf(a2);
}

// ---------------- fc2: bf16 a3 in, weights (pre-transposed) coalesced, grid-stride ----------------
#define FC2_B 8
#define FC2_GRID 2048
__global__ __launch_bounds__(256) void k_fc2(const uint2* __restrict__ a3v,
                                             const float4* __restrict__ wt4,
                                             float* __restrict__ agg,
                                             float* __restrict__ bnpart) {
    __shared__ float4 sa4[FC2_B][49];   // 6.3 KB (f32, unpacked at stage time)
    __shared__ float sp[4][FC2_B][65];  // 8.3 KB
    __shared__ float bnp[4][128];       // 2 KB
    int t = threadIdx.x;
    int cp = t & 63;
    int q = t >> 6;
    float4 wv[12];
#pragma unroll
    for (int m = 0; m < 12; ++m) wv[m] = wt4[(q * 12 + m) * 64 + cp];
    float bnS = 0.f, bnQ = 0.f;
    for (int base = blockIdx.x * FC2_B; base < N_NODES; base += FC2_GRID * FC2_B) {
        __syncthreads();  // protect sa4/sp from previous batch
        // stage 8 nodes x 48 uint2 (4 bf16 each) = 384 -> unpack to float4
        for (int ii = t; ii < FC2_B * 48; ii += 256) {
            int nn = ii / 48, jj = ii - nn * 48;
            int node = base + nn;
            float4 v = make_float4(0.f, 0.f, 0.f, 0.f);
            if (node < N_NODES) {
                uint2 u = a3v[(size_t)node * 48 + jj];
                v.x = __uint_as_float(u.x << 16);
                v.y = __uint_as_float(u.x & 0xFFFF0000u);
                v.z = __uint_as_float(u.y << 16);
                v.w = __uint_as_float(u.y & 0xFFFF0000u);
            }
            sa4[nn][jj] = v;
        }
        __syncthreads();
        float acc[FC2_B];
#pragma unroll
        for (int nn = 0; nn < FC2_B; ++nn) acc[nn] = 0.f;
#pragma unroll
        for (int m = 0; m < 12; ++m) {
            float4 wm = wv[m];
#pragma unroll
            for (int nn = 0; nn < FC2_B; ++nn) {
                float4 s4 = sa4[nn][q * 12 + m];
                acc[nn] = fmaf(s4.x, wm.x, acc[nn]);
                acc[nn] = fmaf(s4.y, wm.y, acc[nn]);
                acc[nn] = fmaf(s4.z, wm.z, acc[nn]);
                acc[nn] = fmaf(s4.w, wm.w, acc[nn]);
            }
        }
#pragma unroll
        for (int nn = 0; nn < FC2_B; ++nn) sp[q][nn][cp] = acc[nn];
        __syncthreads();
#pragma unroll
        for (int i = 0; i < 2; ++i) {
            int nn = q + i * 4;
            int node = base + nn;
            if (node < N_NODES) {
                float v = sp[0][nn][cp] + sp[1][nn][cp] + sp[2][nn][cp] + sp[3][nn][cp];
                agg[(size_t)node * HID + cp] = v;
                bnS += v;
                bnQ += v * v;
            }
        }
    }
    __syncthreads();
    bnp[q][cp] = bnS;
    bnp[q][64 + cp] = bnQ;
    __syncthreads();
    if (t < 128) {
        float v = bnp[0][t] + bnp[1][t] + bnp[2][t] + bnp[3][t];
        bnpart[(size_t)t * FC2_GRID + blockIdx.x] = v;
    }
}

// ---------------- deterministic reduce of bnpart -> bnsum (128 blocks, coalesced) ----------------
__global__ __launch_bounds__(256) void k_bnred2(const float* __restrict__ bnpart,
                                                float* __restrict__ bnsum) {
    __shared__ float red[256];
    int c = blockIdx.x;   // channel 0..127
    int t = threadIdx.x;
    float acc = 0.f;
#pragma unroll
    for (int i = 0; i < FC2_GRID / 256; ++i)
        acc += bnpart[(size_t)c * FC2_GRID + i * 256 + t];
    red[t] = acc;
    __syncthreads();
    for (int off = 128; off > 0; off >>= 1) {
        if (t < off) red[t] += red[t + off];
        __syncthreads();
    }
    if (t == 0) bnsum[c] = red[0];
}

// ---------------- BN finalize + apply + residual (float4) -> h (f32) and h2 (bf16) ----------------
template <bool L0>
__global__ __launch_bounds__(256) void k_bnapply(const float4* __restrict__ agg4,
                                                 const float* __restrict__ bnsum,
                                                 const float* __restrict__ bng,
                                                 const float* __restrict__ bnb,
                                                 const int* __restrict__ h_idx,
                                                 const float4* __restrict__ emb4,
                                                 float4* __restrict__ h4,
                                                 unsigned short* __restrict__ h2) {
    __shared__ float ssc[128];
    int t = threadIdx.x;
    if (t < 64) {
        const float invN = 1.0f / (float)N_NODES;
        float mean = bnsum[t] * invN;
        float var = bnsum[64 + t] * invN - mean * mean;
        float scale = bng[t] * rsqrtf(var + EPS);
        ssc[t] = scale;
        ssc[64 + t] = bnb[t] - mean * scale;
    }
    __syncthreads();
    int i = blockIdx.x * 256 + t;  // over N_NODES*16 float4s
    if (i < N_NODES * 16) {
        int c4 = (i & 15) * 4;
        float4 ag = agg4[i];
        float4 hn;
        hn.x = fmaxf(fmaf(ag.x, ssc[c4 + 0], ssc[64 + c4 + 0]), 0.f);
        hn.y = fmaxf(fmaf(ag.y, ssc[c4 + 1], ssc[64 + c4 + 1]), 0.f);
        hn.z = fmaxf(fmaf(ag.z, ssc[c4 + 2], ssc[64 + c4 + 2]), 0.f);
        hn.w = fmaxf(fmaf(ag.w, ssc[c4 + 3], ssc[64 + c4 + 3]), 0.f);
        float4 base;
        if (L0) {
            int n = i >> 4;
            base = emb4[h_idx[n] * 16 + (i & 15)];
        } else {
            base = h4[i];
        }
        base.x += hn.x; base.y += hn.y; base.z += hn.z; base.w += hn.w;
        h4[i] = base;
        uint2 pk;
        pk.x = (unsigned)f2bf(base.x) | ((unsigned)f2bf(base.y) << 16);
        pk.y = (unsigned)f2bf(base.z) | ((unsigned)f2bf(base.w) << 16);
        *(uint2*)&h2[(size_t)i * 4] = pk;
    }
}

// ---------------- readout: wave per 64-node chunk, run-length accumulate ----------------
__global__ __launch_bounds__(256) void k_readout(const float* __restrict__ h,
                                                 const int* __restrict__ gid,
                                                 float* __restrict__ hg,
                                                 float* __restrict__ cnt) {
    int chunk = blockIdx.x * 4 + (threadIdx.x >> 6);
    int lane = threadIdx.x & 63;
    int n0 = chunk * 64;
    if (n0 >= N_NODES) return;
    int n1 = min(n0 + 64, N_NODES);
    int curg = gid[n0];
    float acc = 0.f;
    int count = 0;
    for (int n = n0; n < n1; ++n) {
        int g = gid[n];
        if (g != curg) {
            atomicAdd(&hg[(size_t)curg * HID + lane], acc);
            if (lane == 0) atomicAdd(&cnt[curg], (float)count);
            curg = g; acc = 0.f; count = 0;
        }
        acc += h[(size_t)n * HID + lane];
        ++count;
    }
    atomicAdd(&hg[(size_t)curg * HID + lane], acc);
    if (lane == 0) atomicAdd(&cnt[curg], (float)count);
}

// ---------------- MLP readout: one wave per graph, 256 blocks ----------------
__global__ __launch_bounds__(64) void k_mlp(const float* __restrict__ hg,
                                            const float* __restrict__ cnt,
                                            const float* __restrict__ w1, const float* __restrict__ b1,
                                            const float* __restrict__ w2, const float* __restrict__ b2,
                                            const float* __restrict__ w3, const float* __restrict__ b3,
                                            float* __restrict__ out) {
    int g = blockIdx.x;      // graph
    int lane = threadIdx.x;  // 0..63
    __shared__ float sx[64];
    __shared__ float sy1[32];
    __shared__ float sy2[16];
    float inv = 1.0f / fmaxf(cnt[g], 1.0f);
    sx[lane] = hg[(size_t)g * HID + lane] * inv;  // coalesced
    __syncthreads();
    if (lane < 32) {
        float acc = b1[lane];
#pragma unroll
        for (int i = 0; i < HID; ++i) acc = fmaf(sx[i], w1[lane * HID + i], acc);
        sy1[lane] = fmaxf(acc, 0.f);
    }
    __syncthreads();
    if (lane < 16) {
        float acc = b2[lane];
#pragma unroll
        for (int i = 0; i < 32; ++i) acc = fmaf(sy1[i], w2[lane * 32 + i], acc);
        sy2[lane] = fmaxf(acc, 0.f);
    }
    __syncthreads();
    if (lane == 0) {
        float acc = b3[0];
#pragma unroll
        for (int i = 0; i < 16; ++i) acc = fmaf(sy2[i], w3[i], acc);
        out[g] = acc;
    }
}

extern "C" void kernel_launch(void* const* d_in, const int* in_sizes, int n_in,
                              void* d_out, int out_size, void* d_ws, size_t ws_size,
                              hipStream_t stream) {
    const int* h_idx = (const int*)d_in[0];
    const int* src = (const int*)d_in[1];
    const int* dst = (const int*)d_in[2];
    const int* gid = (const int*)d_in[3];
    const float* emb = (const float*)d_in[4];
    const float* fc_w = (const float*)d_in[5];
    const float* mu = (const float*)d_in[6];
    const float* isg = (const float*)d_in[7];
    const float* bng = (const float*)d_in[8];
    const float* bnb = (const float*)d_in[9];
    const float* ppw = (const float*)d_in[10];
    const float* ppb = (const float*)d_in[11];
    const float* w1 = (const float*)d_in[12];
    const float* b1 = (const float*)d_in[13];
    const float* w2 = (const float*)d_in[14];
    const float* b2 = (const float*)d_in[15];
    const float* w3 = (const float*)d_in[16];
    const float* b3 = (const float*)d_in[17];

    char* ws = (char*)d_ws;
    size_t o = 0;
    auto take = [&](size_t bytes) -> char* {
        char* p = ws + o;
        o += (bytes + 255) & ~(size_t)255;
        return p;
    };
    int* deg = (int*)take((size_t)N_NODES * 4);
    int* cursor = (int*)take((size_t)N_NODES * 4);
    int* rowptr = (int*)take((size_t)(N_NODES + 1) * 4);
    int* blocksum = (int*)take((size_t)NB1 * 4);
    int* blockoff = (int*)take((size_t)NB1 * 4);
    unsigned* csr_e = (unsigned*)take((size_t)N_EDGES * 4);
    float4* tbl = (float4*)take((size_t)4 * 4096 * 16);
    float4* wt4 = (float4*)take((size_t)4 * 48 * 64 * 16);  // 192 KB
    float* h = (float*)take((size_t)N_NODES * HID * 4);
    unsigned short* h2 = (unsigned short*)take((size_t)N_NODES * HID * 2);  // bf16 mirror
    unsigned short* a3h = (unsigned short*)take((size_t)N_NODES * KOUT * 2); // bf16 a3
    float* agg = (float*)take((size_t)N_NODES * HID * 4);
    float* bnpart = (float*)take((size_t)128 * FC2_GRID * 4);  // 1 MB channel-major
    float* bnsum = (float*)take(128 * 4);
    float* hg = (float*)take((size_t)N_GRAPHS * HID * 4);
    float* cnt = (float*)take((size_t)N_GRAPHS * 4);

    hipMemsetAsync(deg, 0, (size_t)N_NODES * 4, stream);
    hipMemsetAsync(hg, 0, (size_t)(N_GRAPHS * HID + N_GRAPHS) * 4, stream);

    k_deg<<<(N_EDGES + 255) / 256, 256, 0, stream>>>(dst, deg);
    k_scan1<<<NB1, 256, 0, stream>>>(deg, rowptr, blocksum);
    k_scan2<<<1, 256, 0, stream>>>(blocksum, blockoff);
    k_scan3<<<NB1, 256, 0, stream>>>(rowptr, blockoff, cursor);
    k_scatter<<<SC_RANGES * SC_NCHUNK, 256, 0, stream>>>(src, dst, deg, cursor, csr_e);
    k_tables<<<(4 * 4096) / 256, 256, 0, stream>>>(mu, isg, ppw, ppb, tbl);
    k_wprep<<<(4 * 48 * 64 + 255) / 256, 256, 0, stream>>>(fc_w, wt4);

    for (int l = 0; l < 4; ++l) {
        const float* mul = mu + l * 6;
        const float* isgl = isg + l * 6;
        const float* ppwl = ppw + l * 4;
        const float* ppbl = ppb + l * 2;
        const float4* tbll = tbl + (size_t)l * 4096;
        if (l == 0)
            k_pull<true><<<(N_NODES + 3) / 4, 256, 0, stream>>>(rowptr, csr_e, tbll, h2,
                h_idx, emb, deg, mul, isgl, ppwl, ppbl, a3h);
        else
            k_pull<false><<<(N_NODES + 3) / 4, 256, 0, stream>>>(rowptr, csr_e, tbll, h2,
                h_idx, emb, deg, mul, isgl, ppwl, ppbl, a3h);
        k_fc2<<<FC2_GRID, 256, 0, stream>>>(
            (const uint2*)a3h, wt4 + (size_t)l * 48 * 64, agg, bnpart);
        k_bnred2<<<128, 256, 0, stream>>>(bnpart, bnsum);
        if (l == 0)
            k_bnapply<true><<<(N_NODES * 16 + 255) / 256, 256, 0, stream>>>(
                (const float4*)agg, bnsum, bng + l * 64, bnb + l * 64,
                h_idx, (const float4*)emb, (float4*)h, h2);
        else
            k_bnapply<false><<<(N_NODES * 16 + 255) / 256, 256, 0, stream>>>(
                (const float4*)agg, bnsum, bng + l * 64, bnb + l * 64,
                h_idx, (const float4*)emb, (float4*)h, h2);
    }

    k_readout<<<(N_NODES / 64 + 3) / 4 + 1, 256, 0, stream>>>(h, gid, hg, cnt);
    k_mlp<<<N_GRAPHS, 64, 0, stream>>>(hg, cnt, w1, b1, w2, b2, w3, b3, (float*)d_out);
}